// Round 1
// baseline (9997.671 us; speedup 1.0000x reference)
//
#include <hip/hip_runtime.h>
#include <math.h>

// Shapes (B=1 throughout)
#define S_LEN 2048
#define D_MODEL 4096
#define NH 16
#define DN 128
#define DR 64
#define DV 128
#define QLORA_ 1536
#define KVLORA_ 512
#define IDIM 128
#define INH 16
#define TOPK_ 1024

// ---------------- generic tiled fp32 GEMM: C[M,N] = A[M,K] @ B[K,N] ----------------
// Requires M%64==0, N%64==0, K%16==0, lda/ldb/ldc %4==0.
__global__ __launch_bounds__(256) void gemm_f32(const float* __restrict__ A,
                                                const float* __restrict__ B,
                                                float* __restrict__ C,
                                                int K, int lda, int ldb, int ldc) {
  __shared__ float As[16][65];
  __shared__ float Bs[16][64];
  const int t = threadIdx.x;
  const int tx = t & 15, ty = t >> 4;
  const int arow = t >> 2, acol0 = (t & 3) << 2;
  const int brow = t >> 4, bcol0 = (t & 15) << 2;
  const float* Ab = A + (size_t)blockIdx.y * 64 * lda;
  const float* Bb = B + (size_t)blockIdx.x * 64;
  float acc[4][4] = {};
  for (int k0 = 0; k0 < K; k0 += 16) {
    float4 av = *(const float4*)(Ab + (size_t)arow * lda + k0 + acol0);
    As[acol0 + 0][arow] = av.x;
    As[acol0 + 1][arow] = av.y;
    As[acol0 + 2][arow] = av.z;
    As[acol0 + 3][arow] = av.w;
    float4 bv = *(const float4*)(Bb + (size_t)(k0 + brow) * ldb + bcol0);
    *(float4*)&Bs[brow][bcol0] = bv;
    __syncthreads();
#pragma unroll
    for (int kk = 0; kk < 16; ++kk) {
      float a0 = As[kk][ty * 4 + 0], a1 = As[kk][ty * 4 + 1];
      float a2 = As[kk][ty * 4 + 2], a3 = As[kk][ty * 4 + 3];
      float b0 = Bs[kk][tx * 4 + 0], b1 = Bs[kk][tx * 4 + 1];
      float b2 = Bs[kk][tx * 4 + 2], b3 = Bs[kk][tx * 4 + 3];
      acc[0][0] += a0 * b0; acc[0][1] += a0 * b1; acc[0][2] += a0 * b2; acc[0][3] += a0 * b3;
      acc[1][0] += a1 * b0; acc[1][1] += a1 * b1; acc[1][2] += a1 * b2; acc[1][3] += a1 * b3;
      acc[2][0] += a2 * b0; acc[2][1] += a2 * b1; acc[2][2] += a2 * b2; acc[2][3] += a2 * b3;
      acc[3][0] += a3 * b0; acc[3][1] += a3 * b1; acc[3][2] += a3 * b2; acc[3][3] += a3 * b3;
    }
    __syncthreads();
  }
  float* Cb = C + (size_t)(blockIdx.y * 64 + ty * 4) * ldc + blockIdx.x * 64 + tx * 4;
#pragma unroll
  for (int i = 0; i < 4; i++) {
    float4 v = make_float4(acc[i][0], acc[i][1], acc[i][2], acc[i][3]);
    *(float4*)(Cb + (size_t)i * ldc) = v;
  }
}

// ---------------- RMSNorm in place: x *= rsqrt(mean(x^2)+1e-6) * w ----------------
__global__ __launch_bounds__(256) void rmsnorm_kernel(float* __restrict__ x,
                                                      const float* __restrict__ w,
                                                      int ncol, int stride) {
  const int s = blockIdx.x, t = threadIdx.x;
  float* row = x + (size_t)s * stride;
  float ss = 0.f;
  for (int d = t; d < ncol; d += 256) { float v = row[d]; ss += v * v; }
  __shared__ float red[256];
  red[t] = ss;
  __syncthreads();
  for (int o = 128; o > 0; o >>= 1) { if (t < o) red[t] += red[t + o]; __syncthreads(); }
  float r = 1.0f / sqrtf(red[0] / (float)ncol + 1e-6f);
  for (int d = t; d < ncol; d += 256) row[d] = row[d] * r * w[d];
}

// ---------------- LayerNorm in place over 128 cols, eps=1e-5 ----------------
__global__ __launch_bounds__(128) void layernorm128_kernel(float* __restrict__ x,
                                                           const float* __restrict__ w,
                                                           const float* __restrict__ b) {
  const int s = blockIdx.x, t = threadIdx.x;
  float* row = x + (size_t)s * 128;
  __shared__ float red[128];
  float v = row[t];
  red[t] = v;
  __syncthreads();
  for (int o = 64; o > 0; o >>= 1) { if (t < o) red[t] += red[t + o]; __syncthreads(); }
  float mu = red[0] / 128.f;
  __syncthreads();
  float d = v - mu;
  red[t] = d * d;
  __syncthreads();
  for (int o = 64; o > 0; o >>= 1) { if (t < o) red[t] += red[t + o]; __syncthreads(); }
  float var = red[0] / 128.f;
  row[t] = d * (1.0f / sqrtf(var + 1e-5f)) * w[t] + b[t];
}

// ---------------- RoPE kernels ----------------
// q: (S, NH, 192), rope interleaved on last 64 dims of each head. 1 thread = 1 pair.
__global__ __launch_bounds__(256) void rope_q_inter(float* __restrict__ q,
                                                    const float* __restrict__ cosp,
                                                    const float* __restrict__ sinp) {
  int id = blockIdx.x * 256 + threadIdx.x;  // S*NH*32 = 1,048,576
  int s = id >> 9, r = id & 511, h = r >> 5, j = r & 31;
  float c = cosp[s * 32 + j], sn = sinp[s * 32 + j];
  float* base = q + (size_t)s * (NH * 192) + h * 192 + 128 + 2 * j;
  float x0 = base[0], x1 = base[1];
  base[0] = x0 * c - x1 * sn;
  base[1] = x0 * sn + x1 * c;
}

// kv: (S, 576), rope interleaved on cols 512..575
__global__ __launch_bounds__(256) void rope_k_inter(float* __restrict__ kv,
                                                    const float* __restrict__ cosp,
                                                    const float* __restrict__ sinp) {
  int id = blockIdx.x * 256 + threadIdx.x;  // S*32 = 65536
  int s = id >> 5, j = id & 31;
  float c = cosp[s * 32 + j], sn = sinp[s * 32 + j];
  float* base = kv + (size_t)s * 576 + 512 + 2 * j;
  float x0 = base[0], x1 = base[1];
  base[0] = x0 * c - x1 * sn;
  base[1] = x0 * sn + x1 * c;
}

// qi: (S, 16, 128), non-interleaved rope on first 64 dims of each index-head
__global__ __launch_bounds__(256) void rope_qi_nonint(float* __restrict__ qi,
                                                      const float* __restrict__ cosp,
                                                      const float* __restrict__ sinp) {
  int id = blockIdx.x * 256 + threadIdx.x;  // S*16*32 = 1,048,576
  int s = id >> 9, r = id & 511, n = r >> 5, j = r & 31;
  float c = cosp[s * 32 + j], sn = sinp[s * 32 + j];
  float* base = qi + (size_t)s * 2048 + n * 128;
  float xr = base[j], xi = base[j + 32];
  base[j] = xr * c - xi * sn;
  base[j + 32] = xr * sn + xi * c;
}

// ki: (S, 128), non-interleaved rope on first 64 dims
__global__ __launch_bounds__(256) void rope_ki_nonint(float* __restrict__ ki,
                                                      const float* __restrict__ cosp,
                                                      const float* __restrict__ sinp) {
  int id = blockIdx.x * 256 + threadIdx.x;  // S*32 = 65536
  int s = id >> 5, j = id & 31;
  float c = cosp[s * 32 + j], sn = sinp[s * 32 + j];
  float* base = ki + (size_t)s * 128;
  float xr = base[j], xi = base[j + 32];
  base[j] = xr * c - xi * sn;
  base[j + 32] = xr * sn + xi * c;
}

// ---------------- wts = hidden @ idx_w_proj * 0.25 ----------------
__global__ __launch_bounds__(256) void wts_kernel(const float* __restrict__ hs,
                                                  const float* __restrict__ wp,
                                                  float* __restrict__ wts) {
  const int s = blockIdx.x, t = threadIdx.x;
  float acc[16] = {};
  for (int d = t; d < D_MODEL; d += 256) {
    float h = hs[(size_t)s * D_MODEL + d];
    const float* w = wp + (size_t)d * 16;
#pragma unroll
    for (int n = 0; n < 16; n++) acc[n] += h * w[n];
  }
  __shared__ float red[16][256];
#pragma unroll
  for (int n = 0; n < 16; n++) red[n][t] = acc[n];
  __syncthreads();
  for (int o = 128; o > 0; o >>= 1) {
    if (t < o) {
#pragma unroll
      for (int n = 0; n < 16; n++) red[n][t] += red[n][t + o];
    }
    __syncthreads();
  }
  if (t < 16) wts[(size_t)s * 16 + t] = red[t][0] * 0.25f;
}

// ---------------- indexer scores: sc[s][k] for k<=s ----------------
__global__ __launch_bounds__(256) void indexer_scores(const float* __restrict__ qi,
                                                      const float* __restrict__ ki,
                                                      const float* __restrict__ wts,
                                                      float* __restrict__ sc) {
  const int s = blockIdx.x, t = threadIdx.x;
  __shared__ float qs[16 * 128];
  __shared__ float ws[16];
  for (int i = t; i < 2048; i += 256) qs[i] = qi[(size_t)s * 2048 + i];
  if (t < 16) ws[t] = wts[(size_t)s * 16 + t];
  __syncthreads();
  const float iscale = 0.088388347648318447f;  // 128^-0.5
  for (int k = t; k <= s; k += 256) {
    const float4* kr = (const float4*)(ki + (size_t)k * 128);
    float dotn[16] = {};
#pragma unroll 8
    for (int d4 = 0; d4 < 32; d4++) {
      float4 kv4 = kr[d4];
#pragma unroll
      for (int n = 0; n < 16; n++) {
        float4 q4 = *(const float4*)(qs + n * 128 + d4 * 4);
        dotn[n] += q4.x * kv4.x + q4.y * kv4.y + q4.z * kv4.z + q4.w * kv4.w;
      }
    }
    float acc = 0.f;
#pragma unroll
    for (int n = 0; n < 16; n++) {
      float r = dotn[n] * iscale;
      acc += (r > 0.f ? r : 0.f) * ws[n];
    }
    sc[(size_t)s * 2048 + k] = acc;
  }
}

// ---------------- exact top-1024 per row (jax tie semantics) ----------------
__global__ __launch_bounds__(256) void topk_select(const float* __restrict__ sc,
                                                   int* __restrict__ sel,
                                                   int* __restrict__ selcnt) {
  const int s = blockIdx.x, t = threadIdx.x;
  if (s < TOPK_) {
    for (int k = t; k <= s; k += 256) sel[(size_t)s * TOPK_ + k] = k;
    if (t == 0) selcnt[s] = s + 1;
    return;
  }
  __shared__ unsigned keys[2048];
  __shared__ unsigned hist[256];
  __shared__ unsigned sh_prefix, sh_K, sh_cnt;
  const int L = s + 1;
  for (int k = t; k < L; k += 256) {
    unsigned u = __float_as_uint(sc[(size_t)s * 2048 + k]);
    u = (u & 0x80000000u) ? ~u : (u | 0x80000000u);  // monotone map: bigger float -> bigger uint
    keys[k] = u;
  }
  if (t == 0) { sh_prefix = 0u; sh_K = TOPK_; sh_cnt = 0u; }
  __syncthreads();
#pragma unroll
  for (int pass = 0; pass < 4; pass++) {
    const int shift = 24 - 8 * pass;
    const unsigned mask_hi = (pass == 0) ? 0u : (0xFFFFFFFFu << (shift + 8));
    hist[t] = 0u;
    __syncthreads();
    unsigned prefix = sh_prefix;
    for (int k = t; k < L; k += 256) {
      unsigned u = keys[k];
      if ((u & mask_hi) == prefix) atomicAdd(&hist[(u >> shift) & 255u], 1u);
    }
    __syncthreads();
    if (t == 0) {
      unsigned K = sh_K, cum = 0u;
      int b = 255;
      for (; b >= 0; b--) {
        cum += hist[b];
        if (cum >= K) break;
      }
      sh_K = K - (cum - hist[b]);
      sh_prefix = prefix | ((unsigned)b << shift);
    }
    __syncthreads();
  }
  const unsigned T = sh_prefix;
  const unsigned Keq = sh_K;
  for (int k = t; k < L; k += 256) {
    if (keys[k] > T) {
      unsigned p = atomicAdd(&sh_cnt, 1u);
      sel[(size_t)s * TOPK_ + p] = k;
    }
  }
  __syncthreads();
  if (t == 0) {
    unsigned base = sh_cnt, taken = 0u;
    for (int k = 0; k < L && taken < Keq; k++) {
      if (keys[k] == T) { sel[(size_t)s * TOPK_ + base + taken] = k; taken++; }
    }
    selcnt[s] = TOPK_;
  }
}

// ---------------- sparse attention over selected keys ----------------
// q: (S, NH, 192) roped; kvb: (S, NH, 256) [128 k_nope | 128 v]; kvraw: (S,576) k_rope at 512..575
__global__ __launch_bounds__(256) void attn_kernel(const float* __restrict__ q,
                                                   const float* __restrict__ kvb,
                                                   const float* __restrict__ kvraw,
                                                   const int* __restrict__ sel,
                                                   const int* __restrict__ selcnt,
                                                   float* __restrict__ attn) {
  const int s = blockIdx.x, h = blockIdx.y, t = threadIdx.x;
  __shared__ float qv[192];
  __shared__ float pr[TOPK_];
  __shared__ float red[256];
  const int cnt = selcnt[s];
  const float* qrow = q + (size_t)s * (NH * 192) + h * 192;
  if (t < 192) qv[t] = qrow[t];
  __syncthreads();
  const float scale = 0.072168783648703216f;  // 192^-0.5
  float lmax = -INFINITY;
  for (int i = t; i < cnt; i += 256) {
    const int k = sel[(size_t)s * TOPK_ + i];
    const float4* kn = (const float4*)(kvb + (size_t)k * (NH * 256) + h * 256);
    const float4* kr = (const float4*)(kvraw + (size_t)k * 576 + 512);
    float dot = 0.f;
#pragma unroll
    for (int d4 = 0; d4 < 32; d4++) {
      float4 a = ((const float4*)qv)[d4];
      float4 b = kn[d4];
      dot += a.x * b.x + a.y * b.y + a.z * b.z + a.w * b.w;
    }
#pragma unroll
    for (int d4 = 0; d4 < 16; d4++) {
      float4 a = ((const float4*)(qv + 128))[d4];
      float4 b = kr[d4];
      dot += a.x * b.x + a.y * b.y + a.z * b.z + a.w * b.w;
    }
    dot *= scale;
    pr[i] = dot;
    lmax = fmaxf(lmax, dot);
  }
  red[t] = lmax;
  __syncthreads();
  for (int o = 128; o > 0; o >>= 1) { if (t < o) red[t] = fmaxf(red[t], red[t + o]); __syncthreads(); }
  const float m = red[0];
  float lsum = 0.f;
  for (int i = t; i < cnt; i += 256) {
    float e = expf(pr[i] - m);
    pr[i] = e;
    lsum += e;
  }
  __syncthreads();
  red[t] = lsum;
  __syncthreads();
  for (int o = 128; o > 0; o >>= 1) { if (t < o) red[t] += red[t + o]; __syncthreads(); }
  const float inv_l = 1.0f / red[0];
  // output: 2 halves of keys x 128 dims
  const int d = t & 127, half = t >> 7;
  const int mid = (cnt + 1) >> 1;
  const int i0 = half ? mid : 0;
  const int i1 = half ? cnt : mid;
  float acc = 0.f;
  for (int i = i0; i < i1; i++) {
    const int k = sel[(size_t)s * TOPK_ + i];
    acc += pr[i] * kvb[(size_t)k * (NH * 256) + h * 256 + 128 + d];
  }
  __syncthreads();
  red[t] = acc;
  __syncthreads();
  if (t < 128) attn[(size_t)s * (NH * DV) + h * 128 + t] = (red[t] + red[t + 128]) * inv_l;
}

// ---------------- launch ----------------
extern "C" void kernel_launch(void* const* d_in, const int* in_sizes, int n_in,
                              void* d_out, int out_size, void* d_ws, size_t ws_size,
                              hipStream_t stream) {
  const float* hs        = (const float*)d_in[0];
  const float* cosp      = (const float*)d_in[1];
  const float* sinp      = (const float*)d_in[2];
  const float* w_q_a     = (const float*)d_in[3];
  const float* q_a_ln_w  = (const float*)d_in[4];
  const float* w_q_b     = (const float*)d_in[5];
  const float* w_kv_a    = (const float*)d_in[6];
  const float* kv_a_ln_w = (const float*)d_in[7];
  const float* w_kv_b    = (const float*)d_in[8];
  const float* w_o       = (const float*)d_in[9];
  const float* idx_wq_b  = (const float*)d_in[10];
  const float* idx_wk    = (const float*)d_in[11];
  const float* idx_k_ln_w= (const float*)d_in[12];
  const float* idx_k_ln_b= (const float*)d_in[13];
  const float* idx_w_proj= (const float*)d_in[14];
  float* out = (float*)d_out;

  float* ws = (float*)d_ws;
  float* cq    = ws;                    // 2048x1536
  float* qb    = cq + 3145728;          // 2048x3072
  float* kv    = qb + 6291456;          // 2048x576
  float* kvb   = kv + 1179648;          // 2048x4096
  float* qi    = kvb + 8388608;         // 2048x2048
  float* ki    = qi + 4194304;          // 2048x128
  float* wts   = ki + 262144;           // 2048x16
  float* isc   = wts + 32768;           // 2048x2048
  float* attnb = isc + 4194304;         // 2048x2048
  int* sel     = (int*)(attnb + 4194304); // 2048x1024
  int* selcnt  = sel + 2097152;           // 2048

  // 1. cq = hs @ w_q_a  (2048x4096 @ 4096x1536)
  gemm_f32<<<dim3(1536 / 64, 2048 / 64), 256, 0, stream>>>(hs, w_q_a, cq, 4096, 4096, 1536, 1536);
  // 2. rmsnorm(cq)
  rmsnorm_kernel<<<2048, 256, 0, stream>>>(cq, q_a_ln_w, 1536, 1536);
  // 3. q = cq @ w_q_b  (-> 2048x3072)
  gemm_f32<<<dim3(3072 / 64, 2048 / 64), 256, 0, stream>>>(cq, w_q_b, qb, 1536, 1536, 3072, 3072);
  // 4. rope q (interleaved, per head last 64)
  rope_q_inter<<<4096, 256, 0, stream>>>(qb, cosp, sinp);
  // 5. kv = hs @ w_kv_a (-> 2048x576)
  gemm_f32<<<dim3(576 / 64, 2048 / 64), 256, 0, stream>>>(hs, w_kv_a, kv, 4096, 4096, 576, 576);
  // 6. rmsnorm(kv[:, :512])
  rmsnorm_kernel<<<2048, 256, 0, stream>>>(kv, kv_a_ln_w, 512, 576);
  // 7. rope k (interleaved, cols 512..575)
  rope_k_inter<<<256, 256, 0, stream>>>(kv, cosp, sinp);
  // 8. kvb = kv_c @ w_kv_b  (2048x512 @ 512x4096), A stride 576
  gemm_f32<<<dim3(4096 / 64, 2048 / 64), 256, 0, stream>>>(kv, w_kv_b, kvb, 512, 576, 4096, 4096);
  // 9. qi = cq @ idx_wq_b (-> 2048x2048)
  gemm_f32<<<dim3(2048 / 64, 2048 / 64), 256, 0, stream>>>(cq, idx_wq_b, qi, 1536, 1536, 2048, 2048);
  // 10. rope qi (non-interleaved)
  rope_qi_nonint<<<4096, 256, 0, stream>>>(qi, cosp, sinp);
  // 11. ki = hs @ idx_wk (-> 2048x128)
  gemm_f32<<<dim3(128 / 64, 2048 / 64), 256, 0, stream>>>(hs, idx_wk, ki, 4096, 4096, 128, 128);
  // 12. layernorm(ki)
  layernorm128_kernel<<<2048, 128, 0, stream>>>(ki, idx_k_ln_w, idx_k_ln_b);
  // 13. rope ki (non-interleaved)
  rope_ki_nonint<<<256, 256, 0, stream>>>(ki, cosp, sinp);
  // 14. wts
  wts_kernel<<<2048, 256, 0, stream>>>(hs, idx_w_proj, wts);
  // 15. indexer scores
  indexer_scores<<<2048, 256, 0, stream>>>(qi, ki, wts, isc);
  // 16. exact top-k
  topk_select<<<2048, 256, 0, stream>>>(isc, sel, selcnt);
  // 17. sparse attention
  attn_kernel<<<dim3(2048, 16), 256, 0, stream>>>(qb, kvb, kv, sel, selcnt, attnb);
  // 18. out = attn @ w_o (2048x2048 @ 2048x4096)
  gemm_f32<<<dim3(4096 / 64, 2048 / 64), 256, 0, stream>>>(attnb, w_o, out, 2048, 2048, 4096, 4096);
}

// Round 2
// 3354.561 us; speedup vs baseline: 2.9803x; 2.9803x over previous
//
#include <hip/hip_runtime.h>
#include <math.h>

// Shapes (B=1 throughout)
#define S_LEN 2048
#define D_MODEL 4096
#define NH 16
#define DN 128
#define DR 64
#define DV 128
#define QLORA_ 1536
#define KVLORA_ 512
#define IDIM 128
#define INH 16
#define TOPK_ 1024

typedef float f32x4 __attribute__((ext_vector_type(4)));
typedef short bf16x8 __attribute__((ext_vector_type(8)));

__device__ __forceinline__ unsigned short f2bf(float f) {
  unsigned u = __float_as_uint(f);
  u += 0x7fffu + ((u >> 16) & 1u);  // RNE
  return (unsigned short)(u >> 16);
}

// ---------------- generic tiled fp32 GEMM: C[M,N] = A[M,K] @ B[K,N] ----------------
__global__ __launch_bounds__(256) void gemm_f32(const float* __restrict__ A,
                                                const float* __restrict__ B,
                                                float* __restrict__ C,
                                                int K, int lda, int ldb, int ldc) {
  __shared__ float As[16][65];
  __shared__ float Bs[16][64];
  const int t = threadIdx.x;
  const int tx = t & 15, ty = t >> 4;
  const int arow = t >> 2, acol0 = (t & 3) << 2;
  const int brow = t >> 4, bcol0 = (t & 15) << 2;
  const float* Ab = A + (size_t)blockIdx.y * 64 * lda;
  const float* Bb = B + (size_t)blockIdx.x * 64;
  float acc[4][4] = {};
  for (int k0 = 0; k0 < K; k0 += 16) {
    float4 av = *(const float4*)(Ab + (size_t)arow * lda + k0 + acol0);
    As[acol0 + 0][arow] = av.x;
    As[acol0 + 1][arow] = av.y;
    As[acol0 + 2][arow] = av.z;
    As[acol0 + 3][arow] = av.w;
    float4 bv = *(const float4*)(Bb + (size_t)(k0 + brow) * ldb + bcol0);
    *(float4*)&Bs[brow][bcol0] = bv;
    __syncthreads();
#pragma unroll
    for (int kk = 0; kk < 16; ++kk) {
      float a0 = As[kk][ty * 4 + 0], a1 = As[kk][ty * 4 + 1];
      float a2 = As[kk][ty * 4 + 2], a3 = As[kk][ty * 4 + 3];
      float b0 = Bs[kk][tx * 4 + 0], b1 = Bs[kk][tx * 4 + 1];
      float b2 = Bs[kk][tx * 4 + 2], b3 = Bs[kk][tx * 4 + 3];
      acc[0][0] += a0 * b0; acc[0][1] += a0 * b1; acc[0][2] += a0 * b2; acc[0][3] += a0 * b3;
      acc[1][0] += a1 * b0; acc[1][1] += a1 * b1; acc[1][2] += a1 * b2; acc[1][3] += a1 * b3;
      acc[2][0] += a2 * b0; acc[2][1] += a2 * b1; acc[2][2] += a2 * b2; acc[2][3] += a2 * b3;
      acc[3][0] += a3 * b0; acc[3][1] += a3 * b1; acc[3][2] += a3 * b2; acc[3][3] += a3 * b3;
    }
    __syncthreads();
  }
  float* Cb = C + (size_t)(blockIdx.y * 64 + ty * 4) * ldc + blockIdx.x * 64 + tx * 4;
#pragma unroll
  for (int i = 0; i < 4; i++) {
    float4 v = make_float4(acc[i][0], acc[i][1], acc[i][2], acc[i][3]);
    *(float4*)(Cb + (size_t)i * ldc) = v;
  }
}

// Same GEMM with per-z (head) offsets: grid.z = h
__global__ __launch_bounds__(256) void gemm_f32_z(const float* __restrict__ A0,
                                                  const float* __restrict__ B0,
                                                  float* __restrict__ C0,
                                                  int K, int lda, int ldb, int ldc,
                                                  int zsa, int zsb, int zsc) {
  const float* A = A0 + (size_t)blockIdx.z * zsa;
  const float* B = B0 + (size_t)blockIdx.z * zsb;
  float* C = C0 + (size_t)blockIdx.z * zsc;
  __shared__ float As[16][65];
  __shared__ float Bs[16][64];
  const int t = threadIdx.x;
  const int tx = t & 15, ty = t >> 4;
  const int arow = t >> 2, acol0 = (t & 3) << 2;
  const int brow = t >> 4, bcol0 = (t & 15) << 2;
  const float* Ab = A + (size_t)blockIdx.y * 64 * lda;
  const float* Bb = B + (size_t)blockIdx.x * 64;
  float acc[4][4] = {};
  for (int k0 = 0; k0 < K; k0 += 16) {
    float4 av = *(const float4*)(Ab + (size_t)arow * lda + k0 + acol0);
    As[acol0 + 0][arow] = av.x;
    As[acol0 + 1][arow] = av.y;
    As[acol0 + 2][arow] = av.z;
    As[acol0 + 3][arow] = av.w;
    float4 bv = *(const float4*)(Bb + (size_t)(k0 + brow) * ldb + bcol0);
    *(float4*)&Bs[brow][bcol0] = bv;
    __syncthreads();
#pragma unroll
    for (int kk = 0; kk < 16; ++kk) {
      float a0 = As[kk][ty * 4 + 0], a1 = As[kk][ty * 4 + 1];
      float a2 = As[kk][ty * 4 + 2], a3 = As[kk][ty * 4 + 3];
      float b0 = Bs[kk][tx * 4 + 0], b1 = Bs[kk][tx * 4 + 1];
      float b2 = Bs[kk][tx * 4 + 2], b3 = Bs[kk][tx * 4 + 3];
      acc[0][0] += a0 * b0; acc[0][1] += a0 * b1; acc[0][2] += a0 * b2; acc[0][3] += a0 * b3;
      acc[1][0] += a1 * b0; acc[1][1] += a1 * b1; acc[1][2] += a1 * b2; acc[1][3] += a1 * b3;
      acc[2][0] += a2 * b0; acc[2][1] += a2 * b1; acc[2][2] += a2 * b2; acc[2][3] += a2 * b3;
      acc[3][0] += a3 * b0; acc[3][1] += a3 * b1; acc[3][2] += a3 * b2; acc[3][3] += a3 * b3;
    }
    __syncthreads();
  }
  float* Cb = C + (size_t)(blockIdx.y * 64 + ty * 4) * ldc + blockIdx.x * 64 + tx * 4;
#pragma unroll
  for (int i = 0; i < 4; i++) {
    float4 v = make_float4(acc[i][0], acc[i][1], acc[i][2], acc[i][3]);
    *(float4*)(Cb + (size_t)i * ldc) = v;
  }
}

// ---------------- RMSNorm in place ----------------
__global__ __launch_bounds__(256) void rmsnorm_kernel(float* __restrict__ x,
                                                      const float* __restrict__ w,
                                                      int ncol, int stride) {
  const int s = blockIdx.x, t = threadIdx.x;
  float* row = x + (size_t)s * stride;
  float ss = 0.f;
  for (int d = t; d < ncol; d += 256) { float v = row[d]; ss += v * v; }
  __shared__ float red[256];
  red[t] = ss;
  __syncthreads();
  for (int o = 128; o > 0; o >>= 1) { if (t < o) red[t] += red[t + o]; __syncthreads(); }
  float r = 1.0f / sqrtf(red[0] / (float)ncol + 1e-6f);
  for (int d = t; d < ncol; d += 256) row[d] = row[d] * r * w[d];
}

// ---------------- LayerNorm in place over 128 cols ----------------
__global__ __launch_bounds__(128) void layernorm128_kernel(float* __restrict__ x,
                                                           const float* __restrict__ w,
                                                           const float* __restrict__ b) {
  const int s = blockIdx.x, t = threadIdx.x;
  float* row = x + (size_t)s * 128;
  __shared__ float red[128];
  float v = row[t];
  red[t] = v;
  __syncthreads();
  for (int o = 64; o > 0; o >>= 1) { if (t < o) red[t] += red[t + o]; __syncthreads(); }
  float mu = red[0] / 128.f;
  __syncthreads();
  float d = v - mu;
  red[t] = d * d;
  __syncthreads();
  for (int o = 64; o > 0; o >>= 1) { if (t < o) red[t] += red[t + o]; __syncthreads(); }
  float var = red[0] / 128.f;
  row[t] = d * (1.0f / sqrtf(var + 1e-5f)) * w[t] + b[t];
}

// ---------------- RoPE kernels ----------------
__global__ __launch_bounds__(256) void rope_q_inter(float* __restrict__ q,
                                                    const float* __restrict__ cosp,
                                                    const float* __restrict__ sinp) {
  int id = blockIdx.x * 256 + threadIdx.x;  // S*NH*32
  int s = id >> 9, r = id & 511, h = r >> 5, j = r & 31;
  float c = cosp[s * 32 + j], sn = sinp[s * 32 + j];
  float* base = q + (size_t)s * (NH * 192) + h * 192 + 128 + 2 * j;
  float x0 = base[0], x1 = base[1];
  base[0] = x0 * c - x1 * sn;
  base[1] = x0 * sn + x1 * c;
}

__global__ __launch_bounds__(256) void rope_k_inter(float* __restrict__ kv,
                                                    const float* __restrict__ cosp,
                                                    const float* __restrict__ sinp) {
  int id = blockIdx.x * 256 + threadIdx.x;  // S*32
  int s = id >> 5, j = id & 31;
  float c = cosp[s * 32 + j], sn = sinp[s * 32 + j];
  float* base = kv + (size_t)s * 576 + 512 + 2 * j;
  float x0 = base[0], x1 = base[1];
  base[0] = x0 * c - x1 * sn;
  base[1] = x0 * sn + x1 * c;
}

__global__ __launch_bounds__(256) void rope_qi_nonint(float* __restrict__ qi,
                                                      const float* __restrict__ cosp,
                                                      const float* __restrict__ sinp) {
  int id = blockIdx.x * 256 + threadIdx.x;  // S*16*32
  int s = id >> 9, r = id & 511, n = r >> 5, j = r & 31;
  float c = cosp[s * 32 + j], sn = sinp[s * 32 + j];
  float* base = qi + (size_t)s * 2048 + n * 128;
  float xr = base[j], xi = base[j + 32];
  base[j] = xr * c - xi * sn;
  base[j + 32] = xr * sn + xi * c;
}

__global__ __launch_bounds__(256) void rope_ki_nonint(float* __restrict__ ki,
                                                      const float* __restrict__ cosp,
                                                      const float* __restrict__ sinp) {
  int id = blockIdx.x * 256 + threadIdx.x;  // S*32
  int s = id >> 5, j = id & 31;
  float c = cosp[s * 32 + j], sn = sinp[s * 32 + j];
  float* base = ki + (size_t)s * 128;
  float xr = base[j], xi = base[j + 32];
  base[j] = xr * c - xi * sn;
  base[j + 32] = xr * sn + xi * c;
}

// ---------------- wts = hidden @ idx_w_proj * 0.25 ----------------
__global__ __launch_bounds__(256) void wts_kernel(const float* __restrict__ hs,
                                                  const float* __restrict__ wp,
                                                  float* __restrict__ wts) {
  const int s = blockIdx.x, t = threadIdx.x;
  float acc[16] = {};
  for (int d = t; d < D_MODEL; d += 256) {
    float h = hs[(size_t)s * D_MODEL + d];
    const float* w = wp + (size_t)d * 16;
#pragma unroll
    for (int n = 0; n < 16; n++) acc[n] += h * w[n];
  }
  __shared__ float red[16][256];
#pragma unroll
  for (int n = 0; n < 16; n++) red[n][t] = acc[n];
  __syncthreads();
  for (int o = 128; o > 0; o >>= 1) {
    if (t < o) {
#pragma unroll
      for (int n = 0; n < 16; n++) red[n][t] += red[n][t + o];
    }
    __syncthreads();
  }
  if (t < 16) wts[(size_t)s * 16 + t] = red[t][0] * 0.25f;
}

// ---------------- indexer scores ----------------
__global__ __launch_bounds__(256) void indexer_scores(const float* __restrict__ qi,
                                                      const float* __restrict__ ki,
                                                      const float* __restrict__ wts,
                                                      float* __restrict__ sc) {
  const int s = blockIdx.x, t = threadIdx.x;
  __shared__ float qs[16 * 128];
  __shared__ float ws[16];
  for (int i = t; i < 2048; i += 256) qs[i] = qi[(size_t)s * 2048 + i];
  if (t < 16) ws[t] = wts[(size_t)s * 16 + t];
  __syncthreads();
  const float iscale = 0.088388347648318447f;  // 128^-0.5
  for (int k = t; k <= s; k += 256) {
    const float4* kr = (const float4*)(ki + (size_t)k * 128);
    float dotn[16] = {};
#pragma unroll 8
    for (int d4 = 0; d4 < 32; d4++) {
      float4 kv4 = kr[d4];
#pragma unroll
      for (int n = 0; n < 16; n++) {
        float4 q4 = *(const float4*)(qs + n * 128 + d4 * 4);
        dotn[n] += q4.x * kv4.x + q4.y * kv4.y + q4.z * kv4.z + q4.w * kv4.w;
      }
    }
    float acc = 0.f;
#pragma unroll
    for (int n = 0; n < 16; n++) {
      float r = dotn[n] * iscale;
      acc += (r > 0.f ? r : 0.f) * ws[n];
    }
    sc[(size_t)s * 2048 + k] = acc;
  }
}

// ---------------- exact top-1024 per row (jax tie semantics) ----------------
__global__ __launch_bounds__(256) void topk_select(const float* __restrict__ sc,
                                                   int* __restrict__ sel,
                                                   int* __restrict__ selcnt) {
  const int s = blockIdx.x, t = threadIdx.x;
  if (s < TOPK_) {
    for (int k = t; k <= s; k += 256) sel[(size_t)s * TOPK_ + k] = k;
    if (t == 0) selcnt[s] = s + 1;
    return;
  }
  __shared__ unsigned keys[2048];
  __shared__ unsigned hist[256];
  __shared__ unsigned sh_prefix, sh_K, sh_cnt;
  const int L = s + 1;
  for (int k = t; k < L; k += 256) {
    unsigned u = __float_as_uint(sc[(size_t)s * 2048 + k]);
    u = (u & 0x80000000u) ? ~u : (u | 0x80000000u);
    keys[k] = u;
  }
  if (t == 0) { sh_prefix = 0u; sh_K = TOPK_; sh_cnt = 0u; }
  __syncthreads();
#pragma unroll
  for (int pass = 0; pass < 4; pass++) {
    const int shift = 24 - 8 * pass;
    const unsigned mask_hi = (pass == 0) ? 0u : (0xFFFFFFFFu << (shift + 8));
    hist[t] = 0u;
    __syncthreads();
    unsigned prefix = sh_prefix;
    for (int k = t; k < L; k += 256) {
      unsigned u = keys[k];
      if ((u & mask_hi) == prefix) atomicAdd(&hist[(u >> shift) & 255u], 1u);
    }
    __syncthreads();
    if (t == 0) {
      unsigned K = sh_K, cum = 0u;
      int b = 255;
      for (; b >= 0; b--) {
        cum += hist[b];
        if (cum >= K) break;
      }
      sh_K = K - (cum - hist[b]);
      sh_prefix = prefix | ((unsigned)b << shift);
    }
    __syncthreads();
  }
  const unsigned T = sh_prefix;
  const unsigned Keq = sh_K;
  for (int k = t; k < L; k += 256) {
    if (keys[k] > T) {
      unsigned p = atomicAdd(&sh_cnt, 1u);
      sel[(size_t)s * TOPK_ + p] = k;
    }
  }
  __syncthreads();
  if (t == 0) {
    unsigned base = sh_cnt, taken = 0u;
    for (int k = 0; k < L && taken < Keq; k++) {
      if (keys[k] == T) { sel[(size_t)s * TOPK_ + base + taken] = k; taken++; }
    }
    selcnt[s] = TOPK_;
  }
}

// ---------------- kv -> bf16 ----------------
__global__ __launch_bounds__(256) void kv_to_bf16(const float* __restrict__ kv,
                                                  unsigned short* __restrict__ kvbf) {
  int i = blockIdx.x * 256 + threadIdx.x;  // 2048*576
  kvbf[i] = f2bf(kv[i]);
}

// ---------------- q_abs = (q_nope @ w_k[h]^T) * scale -> bf16 ----------------
// qabs[s][h][c] = scale * sum_d qb[s,h,d] * w_kv_b[c, h*256+d]
__global__ __launch_bounds__(256) void qabs_gemm(const float* __restrict__ qb,
                                                 const float* __restrict__ w_kv_b,
                                                 unsigned short* __restrict__ qabs) {
  __shared__ float As[64][132];    // [s-row][d]
  __shared__ float BsT[128][68];   // [d][c-col]
  const int h = blockIdx.z;
  const int s0 = blockIdx.y * 64, c0 = blockIdx.x * 64;
  const int t = threadIdx.x;
  for (int i = t; i < 2048; i += 256) {  // 64 rows x 32 float4
    int row = i >> 5, col4 = i & 31;
    *(float4*)&As[row][col4 * 4] =
        *(const float4*)(qb + (size_t)(s0 + row) * 3072 + h * 192 + col4 * 4);
  }
  for (int i = t; i < 2048; i += 256) {  // 64 c-rows x 32 float4, transpose into BsT
    int c = i >> 5, d4 = (i & 31) * 4;
    float4 v = *(const float4*)(w_kv_b + (size_t)(c0 + c) * 4096 + h * 256 + d4);
    BsT[d4 + 0][c] = v.x;
    BsT[d4 + 1][c] = v.y;
    BsT[d4 + 2][c] = v.z;
    BsT[d4 + 3][c] = v.w;
  }
  __syncthreads();
  const int tx = t & 15, ty = t >> 4;
  float acc[4][4] = {};
  for (int k = 0; k < 128; k++) {
    float4 b = *(const float4*)&BsT[k][tx * 4];
    float a0 = As[ty * 4 + 0][k], a1 = As[ty * 4 + 1][k];
    float a2 = As[ty * 4 + 2][k], a3 = As[ty * 4 + 3][k];
    acc[0][0] += a0 * b.x; acc[0][1] += a0 * b.y; acc[0][2] += a0 * b.z; acc[0][3] += a0 * b.w;
    acc[1][0] += a1 * b.x; acc[1][1] += a1 * b.y; acc[1][2] += a1 * b.z; acc[1][3] += a1 * b.w;
    acc[2][0] += a2 * b.x; acc[2][1] += a2 * b.y; acc[2][2] += a2 * b.z; acc[2][3] += a2 * b.w;
    acc[3][0] += a3 * b.x; acc[3][1] += a3 * b.y; acc[3][2] += a3 * b.z; acc[3][3] += a3 * b.w;
  }
  const float qscale = 0.07216878364870322f;  // 192^-0.5
#pragma unroll
  for (int i = 0; i < 4; i++) {
    unsigned short* dst = qabs + (size_t)(s0 + ty * 4 + i) * 8192 + h * 512 + c0 + tx * 4;
#pragma unroll
    for (int j = 0; j < 4; j++) dst[j] = f2bf(acc[i][j] * qscale);
  }
}

// ---------------- flash attention over selected keys (absorbed) ----------------
// qabs: (S,16,512) bf16 pre-scaled; qb: (S,16,192) fp32 roped (rope part used);
// kvbf: (S,576) bf16 [kv_c | k_rope]; sel: (S,1024); o_c out: (S,16,512) fp32
#define KC 32
__global__ __launch_bounds__(256) void flash_attn(const unsigned short* __restrict__ qabs,
                                                  const float* __restrict__ qb,
                                                  const unsigned short* __restrict__ kvbf,
                                                  const int* __restrict__ sel,
                                                  float* __restrict__ o_c) {
  const int s = blockIdx.x, t = threadIdx.x;
  const int lane = t & 63, w = t >> 6;
  __shared__ unsigned short qs[16][584];
  __shared__ unsigned short kvs[KC][584];
  __shared__ float s_part[2][16][36];
  __shared__ float p_lds[KC][20];
  __shared__ float red[16][17];
  __shared__ float m_sh[16], l_sh[16], al_sh[16];
  const int cnt = (s < 1024) ? (s + 1) : 1024;
  const float qscale = 0.07216878364870322f;

  // stage q_abs (bf16, pre-scaled): 16x512 shorts = 1024 16B chunks
  for (int i = t; i < 1024; i += 256) {
    int h = i >> 6, c8 = i & 63;
    *(float4*)&qs[h][c8 * 8] = *(const float4*)(qabs + (size_t)s * 8192 + h * 512 + c8 * 8);
  }
  // stage q_rope (fp32 -> scaled bf16): 16x64
  {
    int h = t >> 4, j = (t & 15) * 4;
    float4 v = *(const float4*)(qb + (size_t)s * 3072 + h * 192 + 128 + j);
    qs[h][512 + j + 0] = f2bf(v.x * qscale);
    qs[h][512 + j + 1] = f2bf(v.y * qscale);
    qs[h][512 + j + 2] = f2bf(v.z * qscale);
    qs[h][512 + j + 3] = f2bf(v.w * qscale);
  }
  if (t < 16) { m_sh[t] = -3.0e38f; l_sh[t] = 0.f; }
  float o[8][4];
#pragma unroll
  for (int j = 0; j < 8; j++)
#pragma unroll
    for (int c = 0; c < 4; c++) o[j][c] = 0.f;
  const int hgrp = t >> 7, c4 = t & 127;
  const int h_ = t & 15, grp = t >> 4;

  for (int k0 = 0; k0 < cnt; k0 += KC) {
    __syncthreads();
    // ---- stage kv chunk (8 threads per row, 9 x 16B each) ----
    {
      int row = t >> 3, sub = t & 7;
      int gk = k0 + row;
      if (gk < cnt) {
        const unsigned short* sp = kvbf + (size_t)sel[(size_t)s * TOPK_ + gk] * 576;
#pragma unroll
        for (int j = 0; j < 9; j++)
          *(float4*)&kvs[row][(sub + 8 * j) * 8] = *(const float4*)(sp + (sub + 8 * j) * 8);
      } else {
        float4 z = make_float4(0.f, 0.f, 0.f, 0.f);
#pragma unroll
        for (int j = 0; j < 9; j++) *(float4*)&kvs[row][(sub + 8 * j) * 8] = z;
      }
    }
    __syncthreads();
    // ---- QK via MFMA: wave w -> k-subtile (w&1), K-half (w>>1) ----
    {
      const int half = w >> 1, kt = w & 1;
      const int col = lane & 15, quad = lane >> 4;
      f32x4 acc = {0.f, 0.f, 0.f, 0.f};
      const unsigned short* ap = &qs[col][half * 288 + quad * 8];
      const unsigned short* bp = &kvs[kt * 16 + col][half * 288 + quad * 8];
#pragma unroll
      for (int kk = 0; kk < 9; kk++) {
        bf16x8 a = *(const bf16x8*)(ap + kk * 32);
        bf16x8 b = *(const bf16x8*)(bp + kk * 32);
        acc = __builtin_amdgcn_mfma_f32_16x16x32_bf16(a, b, acc, 0, 0, 0);
      }
#pragma unroll
      for (int r = 0; r < 4; r++) s_part[half][quad * 4 + r][kt * 16 + col] = acc[r];
    }
    __syncthreads();
    // ---- online softmax ----
    float v0, v1;
    {
      int kk0 = grp * 2, kk1 = grp * 2 + 1;
      v0 = (k0 + kk0 < cnt) ? (s_part[0][h_][kk0] + s_part[1][h_][kk0]) : -3.0e38f;
      v1 = (k0 + kk1 < cnt) ? (s_part[0][h_][kk1] + s_part[1][h_][kk1]) : -3.0e38f;
      red[h_][grp] = fmaxf(v0, v1);
    }
    __syncthreads();
    if (t < 16) {
      float mc = red[t][0];
#pragma unroll
      for (int g = 1; g < 16; g++) mc = fmaxf(mc, red[t][g]);
      float mo = m_sh[t];
      float mn = fmaxf(mo, mc);
      m_sh[t] = mn;
      al_sh[t] = __expf(mo - mn);
    }
    __syncthreads();
    {
      float mm = m_sh[h_];
      float e0 = __expf(v0 - mm);
      float e1 = __expf(v1 - mm);
      p_lds[grp * 2][h_] = e0;
      p_lds[grp * 2 + 1][h_] = e1;
      red[h_][grp] = e0 + e1;
    }
    __syncthreads();
    if (t < 16) {
      float sl = 0.f;
#pragma unroll
      for (int g = 0; g < 16; g++) sl += red[t][g];
      l_sh[t] = l_sh[t] * al_sh[t] + sl;
    }
    __syncthreads();
    // ---- PV (vector fp32): thread owns 8 heads x 4 c ----
    {
      float a_[8];
#pragma unroll
      for (int j = 0; j < 8; j++) a_[j] = al_sh[hgrp * 8 + j];
#pragma unroll
      for (int j = 0; j < 8; j++) {
        o[j][0] *= a_[j]; o[j][1] *= a_[j]; o[j][2] *= a_[j]; o[j][3] *= a_[j];
      }
      for (int k = 0; k < KC; k++) {
        uint2 kk = *(const uint2*)&kvs[k][c4 * 4];
        float kv0 = __uint_as_float(kk.x << 16);
        float kv1 = __uint_as_float(kk.x & 0xFFFF0000u);
        float kv2 = __uint_as_float(kk.y << 16);
        float kv3 = __uint_as_float(kk.y & 0xFFFF0000u);
        float4 p0 = *(const float4*)&p_lds[k][hgrp * 8];
        float4 p1 = *(const float4*)&p_lds[k][hgrp * 8 + 4];
        float pj[8] = {p0.x, p0.y, p0.z, p0.w, p1.x, p1.y, p1.z, p1.w};
#pragma unroll
        for (int j = 0; j < 8; j++) {
          o[j][0] += pj[j] * kv0;
          o[j][1] += pj[j] * kv1;
          o[j][2] += pj[j] * kv2;
          o[j][3] += pj[j] * kv3;
        }
      }
    }
  }
  __syncthreads();
  if (t < 16) l_sh[t] = 1.0f / l_sh[t];
  __syncthreads();
#pragma unroll
  for (int j = 0; j < 8; j++) {
    float li = l_sh[hgrp * 8 + j];
    float4 vv = make_float4(o[j][0] * li, o[j][1] * li, o[j][2] * li, o[j][3] * li);
    *(float4*)(o_c + (size_t)s * 8192 + (hgrp * 8 + j) * 512 + c4 * 4) = vv;
  }
}

// ---------------- launch ----------------
extern "C" void kernel_launch(void* const* d_in, const int* in_sizes, int n_in,
                              void* d_out, int out_size, void* d_ws, size_t ws_size,
                              hipStream_t stream) {
  const float* hs         = (const float*)d_in[0];
  const float* cosp       = (const float*)d_in[1];
  const float* sinp       = (const float*)d_in[2];
  const float* w_q_a      = (const float*)d_in[3];
  const float* q_a_ln_w   = (const float*)d_in[4];
  const float* w_q_b      = (const float*)d_in[5];
  const float* w_kv_a     = (const float*)d_in[6];
  const float* kv_a_ln_w  = (const float*)d_in[7];
  const float* w_kv_b     = (const float*)d_in[8];
  const float* w_o        = (const float*)d_in[9];
  const float* idx_wq_b   = (const float*)d_in[10];
  const float* idx_wk     = (const float*)d_in[11];
  const float* idx_k_ln_w = (const float*)d_in[12];
  const float* idx_k_ln_b = (const float*)d_in[13];
  const float* idx_w_proj = (const float*)d_in[14];
  float* out = (float*)d_out;

  float* ws = (float*)d_ws;
  float* cq    = ws;                        // 2048x1536
  float* qb    = cq + 3145728;              // 2048x16x192
  float* kv    = qb + 6291456;              // 2048x576
  float* qi    = kv + 1179648;              // 2048x2048
  float* ki    = qi + 4194304;              // 2048x128
  float* wts   = ki + 262144;               // 2048x16
  float* isc   = wts + 32768;               // 2048x2048
  float* attnb = isc;                       // alias: isc dead after topk
  float* o_c   = isc + 4194304;             // 2048x16x512
  unsigned short* qabs = (unsigned short*)(o_c + 16777216);   // 2048x16x512 bf16
  unsigned short* kvbf = qabs + 16777216;                     // 2048x576 bf16
  int* sel     = (int*)(kvbf + 1179648);    // 2048x1024
  int* selcnt  = sel + 2097152;             // 2048

  // 1. cq = hs @ w_q_a ; rmsnorm
  gemm_f32<<<dim3(24, 32), 256, 0, stream>>>(hs, w_q_a, cq, 4096, 4096, 1536, 1536);
  rmsnorm_kernel<<<2048, 256, 0, stream>>>(cq, q_a_ln_w, 1536, 1536);
  // 2. qb = cq @ w_q_b ; rope
  gemm_f32<<<dim3(48, 32), 256, 0, stream>>>(cq, w_q_b, qb, 1536, 1536, 3072, 3072);
  rope_q_inter<<<4096, 256, 0, stream>>>(qb, cosp, sinp);
  // 3. kv = hs @ w_kv_a ; rmsnorm(512) ; rope(rope part)
  gemm_f32<<<dim3(9, 32), 256, 0, stream>>>(hs, w_kv_a, kv, 4096, 4096, 576, 576);
  rmsnorm_kernel<<<2048, 256, 0, stream>>>(kv, kv_a_ln_w, 512, 576);
  rope_k_inter<<<256, 256, 0, stream>>>(kv, cosp, sinp);
  // 4. kv -> bf16
  kv_to_bf16<<<4608, 256, 0, stream>>>(kv, kvbf);
  // 5. q_abs (absorbed q, bf16, pre-scaled)
  qabs_gemm<<<dim3(8, 32, 16), 256, 0, stream>>>(qb, w_kv_b, qabs);
  // 6. indexer path
  gemm_f32<<<dim3(32, 32), 256, 0, stream>>>(cq, idx_wq_b, qi, 1536, 1536, 2048, 2048);
  rope_qi_nonint<<<4096, 256, 0, stream>>>(qi, cosp, sinp);
  gemm_f32<<<dim3(2, 32), 256, 0, stream>>>(hs, idx_wk, ki, 4096, 4096, 128, 128);
  layernorm128_kernel<<<2048, 128, 0, stream>>>(ki, idx_k_ln_w, idx_k_ln_b);
  rope_ki_nonint<<<256, 256, 0, stream>>>(ki, cosp, sinp);
  wts_kernel<<<2048, 256, 0, stream>>>(hs, idx_w_proj, wts);
  indexer_scores<<<2048, 256, 0, stream>>>(qi, ki, wts, isc);
  topk_select<<<2048, 256, 0, stream>>>(isc, sel, selcnt);
  // 7. flash attention (absorbed)
  flash_attn<<<2048, 256, 0, stream>>>(qabs, qb, kvbf, sel, o_c);
  // 8. attn_out[s,h,:] = o_c[s,h,:] @ w_v[h]
  gemm_f32_z<<<dim3(2, 32, 16), 256, 0, stream>>>(o_c, w_kv_b + 128, attnb,
                                                  512, 8192, 4096, 2048, 512, 256, 128);
  // 9. out = attn_out @ w_o
  gemm_f32<<<dim3(64, 32), 256, 0, stream>>>(attnb, w_o, out, 2048, 2048, 4096, 4096);
}

// Round 3
// 1927.942 us; speedup vs baseline: 5.1857x; 1.7400x over previous
//
#include <hip/hip_runtime.h>
#include <math.h>

// Shapes (B=1 throughout)
#define S_LEN 2048
#define D_MODEL 4096
#define NH 16
#define DN 128
#define DR 64
#define DV 128
#define QLORA_ 1536
#define KVLORA_ 512
#define IDIM 128
#define INH 16
#define TOPK_ 1024

typedef float f32x4 __attribute__((ext_vector_type(4)));
typedef short bf16x8 __attribute__((ext_vector_type(8)));

__device__ __forceinline__ unsigned short f2bf(float f) {
  unsigned u = __float_as_uint(f);
  u += 0x7fffu + ((u >> 16) & 1u);  // RNE
  return (unsigned short)(u >> 16);
}

// ---------------- bf16 MFMA GEMM: C[M,N] = A[M,K] @ Bt[N,K]^T ----------------
// A bf16 [M,K] row-major, Bt bf16 [N,K] row-major (i.e. B transposed), C fp32 [M,N].
// M%128==0, N%128==0, K%32==0. Tile 128x128, BK=32, 256 threads (4 waves).
// LDS rows padded to 40 shorts (80B) -> fragment ds_read_b128 is 2-way bank-aliased (free, m136).
#define LDSW 40
__global__ __launch_bounds__(256) void gemm_bf16(const unsigned short* __restrict__ A,
                                                 const unsigned short* __restrict__ Bt,
                                                 float* __restrict__ C,
                                                 int K, int N) {
  __shared__ unsigned short As[128 * LDSW];
  __shared__ unsigned short Bs[128 * LDSW];
  const int t = threadIdx.x, lane = t & 63, w = t >> 6;
  const int m0 = blockIdx.y * 128, n0 = blockIdx.x * 128;
  const int mb = (w & 1) * 64, nb = (w >> 1) * 64;
  const int fr = lane & 15, fq = lane >> 4;
  f32x4 acc[4][4];
#pragma unroll
  for (int i = 0; i < 4; i++)
#pragma unroll
    for (int j = 0; j < 4; j++) acc[i][j] = (f32x4){0.f, 0.f, 0.f, 0.f};

  const int srow0 = t >> 2, ssub = (t & 3) * 8;          // staging: chunk t -> row t>>2, 16B sub
  const int srow1 = (t + 256) >> 2;                      // second chunk
  for (int k0 = 0; k0 < K; k0 += 32) {
    __syncthreads();
    {
      float4 a0 = *(const float4*)(A + (size_t)(m0 + srow0) * K + k0 + ssub);
      float4 a1 = *(const float4*)(A + (size_t)(m0 + srow1) * K + k0 + ssub);
      float4 b0 = *(const float4*)(Bt + (size_t)(n0 + srow0) * K + k0 + ssub);
      float4 b1 = *(const float4*)(Bt + (size_t)(n0 + srow1) * K + k0 + ssub);
      *(float4*)&As[srow0 * LDSW + ssub] = a0;
      *(float4*)&As[srow1 * LDSW + ssub] = a1;
      *(float4*)&Bs[srow0 * LDSW + ssub] = b0;
      *(float4*)&Bs[srow1 * LDSW + ssub] = b1;
    }
    __syncthreads();
    bf16x8 af[4], bfr[4];
#pragma unroll
    for (int mt = 0; mt < 4; mt++)
      af[mt] = *(const bf16x8*)&As[(mb + mt * 16 + fr) * LDSW + fq * 8];
#pragma unroll
    for (int nt = 0; nt < 4; nt++)
      bfr[nt] = *(const bf16x8*)&Bs[(nb + nt * 16 + fr) * LDSW + fq * 8];
#pragma unroll
    for (int mt = 0; mt < 4; mt++)
#pragma unroll
      for (int nt = 0; nt < 4; nt++)
        acc[mt][nt] = __builtin_amdgcn_mfma_f32_16x16x32_bf16(af[mt], bfr[nt], acc[mt][nt], 0, 0, 0);
  }
#pragma unroll
  for (int mt = 0; mt < 4; mt++) {
#pragma unroll
    for (int r = 0; r < 4; r++) {
      int row = m0 + mb + mt * 16 + fq * 4 + r;
      float* cp = C + (size_t)row * N + n0 + nb + fr;
#pragma unroll
      for (int nt = 0; nt < 4; nt++) cp[nt * 16] = acc[mt][nt][r];
    }
  }
}

// ---------------- cast fp32 -> bf16 (8 elems/thread) ----------------
__global__ __launch_bounds__(256) void cast_bf16(const float* __restrict__ in,
                                                 unsigned short* __restrict__ out) {
  size_t i = (size_t)(blockIdx.x * 256 + threadIdx.x) * 8;
  float4 v0 = *(const float4*)(in + i);
  float4 v1 = *(const float4*)(in + i + 4);
  unsigned short tmp[8] = {f2bf(v0.x), f2bf(v0.y), f2bf(v0.z), f2bf(v0.w),
                           f2bf(v1.x), f2bf(v1.y), f2bf(v1.z), f2bf(v1.w)};
  *(float4*)(out + i) = *(float4*)tmp;
}

// ---------------- transpose+cast: in fp32 [K,N] -> out bf16 [Npad,K] ----------------
// tile 64k x 32n; N%32==0, K%64==0; rows n in [N,Npad) written as zeros.
__global__ __launch_bounds__(256) void transpose_cast(const float* __restrict__ in,
                                                      unsigned short* __restrict__ out,
                                                      int K, int N) {
  __shared__ float buf[64][33];
  const int k0 = blockIdx.y * 64, n0 = blockIdx.x * 32;
  const int t = threadIdx.x;
  const bool valid = (n0 < N);
  if (valid) {
#pragma unroll
    for (int i = 0; i < 2; i++) {
      int c = i * 256 + t;
      int kk = c >> 3, nn = (c & 7) * 4;
      float4 v = *(const float4*)(in + (size_t)(k0 + kk) * N + n0 + nn);
      buf[kk][nn] = v.x; buf[kk][nn + 1] = v.y; buf[kk][nn + 2] = v.z; buf[kk][nn + 3] = v.w;
    }
  }
  __syncthreads();
  const int n = t >> 3, k8 = (t & 7) * 8;
  unsigned short tmp[8];
#pragma unroll
  for (int j = 0; j < 8; j++) tmp[j] = valid ? f2bf(buf[k8 + j][n]) : (unsigned short)0;
  *(float4*)(out + (size_t)(n0 + n) * K + k0 + k8) = *(float4*)tmp;
}

// ---------------- generic tiled fp32 GEMM (kept for ki) ----------------
__global__ __launch_bounds__(256) void gemm_f32(const float* __restrict__ A,
                                                const float* __restrict__ B,
                                                float* __restrict__ C,
                                                int K, int lda, int ldb, int ldc) {
  __shared__ float As[16][65];
  __shared__ float Bs[16][64];
  const int t = threadIdx.x;
  const int tx = t & 15, ty = t >> 4;
  const int arow = t >> 2, acol0 = (t & 3) << 2;
  const int brow = t >> 4, bcol0 = (t & 15) << 2;
  const float* Ab = A + (size_t)blockIdx.y * 64 * lda;
  const float* Bb = B + (size_t)blockIdx.x * 64;
  float acc[4][4] = {};
  for (int k0 = 0; k0 < K; k0 += 16) {
    float4 av = *(const float4*)(Ab + (size_t)arow * lda + k0 + acol0);
    As[acol0 + 0][arow] = av.x;
    As[acol0 + 1][arow] = av.y;
    As[acol0 + 2][arow] = av.z;
    As[acol0 + 3][arow] = av.w;
    float4 bv = *(const float4*)(Bb + (size_t)(k0 + brow) * ldb + bcol0);
    *(float4*)&Bs[brow][bcol0] = bv;
    __syncthreads();
#pragma unroll
    for (int kk = 0; kk < 16; ++kk) {
      float a0 = As[kk][ty * 4 + 0], a1 = As[kk][ty * 4 + 1];
      float a2 = As[kk][ty * 4 + 2], a3 = As[kk][ty * 4 + 3];
      float b0 = Bs[kk][tx * 4 + 0], b1 = Bs[kk][tx * 4 + 1];
      float b2 = Bs[kk][tx * 4 + 2], b3 = Bs[kk][tx * 4 + 3];
      acc[0][0] += a0 * b0; acc[0][1] += a0 * b1; acc[0][2] += a0 * b2; acc[0][3] += a0 * b3;
      acc[1][0] += a1 * b0; acc[1][1] += a1 * b1; acc[1][2] += a1 * b2; acc[1][3] += a1 * b3;
      acc[2][0] += a2 * b0; acc[2][1] += a2 * b1; acc[2][2] += a2 * b2; acc[2][3] += a2 * b3;
      acc[3][0] += a3 * b0; acc[3][1] += a3 * b1; acc[3][2] += a3 * b2; acc[3][3] += a3 * b3;
    }
    __syncthreads();
  }
  float* Cb = C + (size_t)(blockIdx.y * 64 + ty * 4) * ldc + blockIdx.x * 64 + tx * 4;
#pragma unroll
  for (int i = 0; i < 4; i++) {
    float4 v = make_float4(acc[i][0], acc[i][1], acc[i][2], acc[i][3]);
    *(float4*)(Cb + (size_t)i * ldc) = v;
  }
}

// per-z (head) GEMM writing bf16 C: attnb[s][h*128+d]
__global__ __launch_bounds__(256) void gemm_f32_z_bf(const float* __restrict__ A0,
                                                     const float* __restrict__ B0,
                                                     unsigned short* __restrict__ C0,
                                                     int K, int lda, int ldb, int ldc,
                                                     int zsa, int zsb, int zsc) {
  const float* A = A0 + (size_t)blockIdx.z * zsa;
  const float* B = B0 + (size_t)blockIdx.z * zsb;
  unsigned short* C = C0 + (size_t)blockIdx.z * zsc;
  __shared__ float As[16][65];
  __shared__ float Bs[16][64];
  const int t = threadIdx.x;
  const int tx = t & 15, ty = t >> 4;
  const int arow = t >> 2, acol0 = (t & 3) << 2;
  const int brow = t >> 4, bcol0 = (t & 15) << 2;
  const float* Ab = A + (size_t)blockIdx.y * 64 * lda;
  const float* Bb = B + (size_t)blockIdx.x * 64;
  float acc[4][4] = {};
  for (int k0 = 0; k0 < K; k0 += 16) {
    float4 av = *(const float4*)(Ab + (size_t)arow * lda + k0 + acol0);
    As[acol0 + 0][arow] = av.x;
    As[acol0 + 1][arow] = av.y;
    As[acol0 + 2][arow] = av.z;
    As[acol0 + 3][arow] = av.w;
    float4 bv = *(const float4*)(Bb + (size_t)(k0 + brow) * ldb + bcol0);
    *(float4*)&Bs[brow][bcol0] = bv;
    __syncthreads();
#pragma unroll
    for (int kk = 0; kk < 16; ++kk) {
      float a0 = As[kk][ty * 4 + 0], a1 = As[kk][ty * 4 + 1];
      float a2 = As[kk][ty * 4 + 2], a3 = As[kk][ty * 4 + 3];
      float b0 = Bs[kk][tx * 4 + 0], b1 = Bs[kk][tx * 4 + 1];
      float b2 = Bs[kk][tx * 4 + 2], b3 = Bs[kk][tx * 4 + 3];
      acc[0][0] += a0 * b0; acc[0][1] += a0 * b1; acc[0][2] += a0 * b2; acc[0][3] += a0 * b3;
      acc[1][0] += a1 * b0; acc[1][1] += a1 * b1; acc[1][2] += a1 * b2; acc[1][3] += a1 * b3;
      acc[2][0] += a2 * b0; acc[2][1] += a2 * b1; acc[2][2] += a2 * b2; acc[2][3] += a2 * b3;
      acc[3][0] += a3 * b0; acc[3][1] += a3 * b1; acc[3][2] += a3 * b2; acc[3][3] += a3 * b3;
    }
    __syncthreads();
  }
  unsigned short* Cb = C + (size_t)(blockIdx.y * 64 + ty * 4) * ldc + blockIdx.x * 64 + tx * 4;
#pragma unroll
  for (int i = 0; i < 4; i++)
#pragma unroll
    for (int j = 0; j < 4; j++) Cb[(size_t)i * ldc + j] = f2bf(acc[i][j]);
}

// ---------------- RMSNorm in place ----------------
__global__ __launch_bounds__(256) void rmsnorm_kernel(float* __restrict__ x,
                                                      const float* __restrict__ w,
                                                      int ncol, int stride) {
  const int s = blockIdx.x, t = threadIdx.x;
  float* row = x + (size_t)s * stride;
  float ss = 0.f;
  for (int d = t; d < ncol; d += 256) { float v = row[d]; ss += v * v; }
  __shared__ float red[256];
  red[t] = ss;
  __syncthreads();
  for (int o = 128; o > 0; o >>= 1) { if (t < o) red[t] += red[t + o]; __syncthreads(); }
  float r = 1.0f / sqrtf(red[0] / (float)ncol + 1e-6f);
  for (int d = t; d < ncol; d += 256) row[d] = row[d] * r * w[d];
}

// RMSNorm in place + bf16 copy out
__global__ __launch_bounds__(256) void rmsnorm_bf16_kernel(float* __restrict__ x,
                                                           const float* __restrict__ w,
                                                           unsigned short* __restrict__ xbf,
                                                           int ncol, int stride) {
  const int s = blockIdx.x, t = threadIdx.x;
  float* row = x + (size_t)s * stride;
  float ss = 0.f;
  for (int d = t; d < ncol; d += 256) { float v = row[d]; ss += v * v; }
  __shared__ float red[256];
  red[t] = ss;
  __syncthreads();
  for (int o = 128; o > 0; o >>= 1) { if (t < o) red[t] += red[t + o]; __syncthreads(); }
  float r = 1.0f / sqrtf(red[0] / (float)ncol + 1e-6f);
  for (int d = t; d < ncol; d += 256) {
    float v = row[d] * r * w[d];
    row[d] = v;
    xbf[(size_t)s * ncol + d] = f2bf(v);
  }
}

// ---------------- LayerNorm in place over 128 cols ----------------
__global__ __launch_bounds__(128) void layernorm128_kernel(float* __restrict__ x,
                                                           const float* __restrict__ w,
                                                           const float* __restrict__ b) {
  const int s = blockIdx.x, t = threadIdx.x;
  float* row = x + (size_t)s * 128;
  __shared__ float red[128];
  float v = row[t];
  red[t] = v;
  __syncthreads();
  for (int o = 64; o > 0; o >>= 1) { if (t < o) red[t] += red[t + o]; __syncthreads(); }
  float mu = red[0] / 128.f;
  __syncthreads();
  float d = v - mu;
  red[t] = d * d;
  __syncthreads();
  for (int o = 64; o > 0; o >>= 1) { if (t < o) red[t] += red[t + o]; __syncthreads(); }
  float var = red[0] / 128.f;
  row[t] = d * (1.0f / sqrtf(var + 1e-5f)) * w[t] + b[t];
}

// ---------------- RoPE kernels ----------------
__global__ __launch_bounds__(256) void rope_q_inter(float* __restrict__ q,
                                                    const float* __restrict__ cosp,
                                                    const float* __restrict__ sinp) {
  int id = blockIdx.x * 256 + threadIdx.x;  // S*NH*32
  int s = id >> 9, r = id & 511, h = r >> 5, j = r & 31;
  float c = cosp[s * 32 + j], sn = sinp[s * 32 + j];
  float* base = q + (size_t)s * (NH * 192) + h * 192 + 128 + 2 * j;
  float x0 = base[0], x1 = base[1];
  base[0] = x0 * c - x1 * sn;
  base[1] = x0 * sn + x1 * c;
}

__global__ __launch_bounds__(256) void rope_k_inter(float* __restrict__ kv,
                                                    const float* __restrict__ cosp,
                                                    const float* __restrict__ sinp,
                                                    int stride) {
  int id = blockIdx.x * 256 + threadIdx.x;  // S*32
  int s = id >> 5, j = id & 31;
  float c = cosp[s * 32 + j], sn = sinp[s * 32 + j];
  float* base = kv + (size_t)s * stride + 512 + 2 * j;
  float x0 = base[0], x1 = base[1];
  base[0] = x0 * c - x1 * sn;
  base[1] = x0 * sn + x1 * c;
}

__global__ __launch_bounds__(256) void rope_qi_nonint(float* __restrict__ qi,
                                                      const float* __restrict__ cosp,
                                                      const float* __restrict__ sinp) {
  int id = blockIdx.x * 256 + threadIdx.x;  // S*16*32
  int s = id >> 9, r = id & 511, n = r >> 5, j = r & 31;
  float c = cosp[s * 32 + j], sn = sinp[s * 32 + j];
  float* base = qi + (size_t)s * 2048 + n * 128;
  float xr = base[j], xi = base[j + 32];
  base[j] = xr * c - xi * sn;
  base[j + 32] = xr * sn + xi * c;
}

__global__ __launch_bounds__(256) void rope_ki_nonint(float* __restrict__ ki,
                                                      const float* __restrict__ cosp,
                                                      const float* __restrict__ sinp) {
  int id = blockIdx.x * 256 + threadIdx.x;  // S*32
  int s = id >> 5, j = id & 31;
  float c = cosp[s * 32 + j], sn = sinp[s * 32 + j];
  float* base = ki + (size_t)s * 128;
  float xr = base[j], xi = base[j + 32];
  base[j] = xr * c - xi * sn;
  base[j + 32] = xr * sn + xi * c;
}

// ---------------- wts = hidden @ idx_w_proj * 0.25 ----------------
__global__ __launch_bounds__(256) void wts_kernel(const float* __restrict__ hs,
                                                  const float* __restrict__ wp,
                                                  float* __restrict__ wts) {
  const int s = blockIdx.x, t = threadIdx.x;
  float acc[16] = {};
  for (int d = t; d < D_MODEL; d += 256) {
    float h = hs[(size_t)s * D_MODEL + d];
    const float* w = wp + (size_t)d * 16;
#pragma unroll
    for (int n = 0; n < 16; n++) acc[n] += h * w[n];
  }
  __shared__ float red[16][256];
#pragma unroll
  for (int n = 0; n < 16; n++) red[n][t] = acc[n];
  __syncthreads();
  for (int o = 128; o > 0; o >>= 1) {
    if (t < o) {
#pragma unroll
      for (int n = 0; n < 16; n++) red[n][t] += red[n][t + o];
    }
    __syncthreads();
  }
  if (t < 16) wts[(size_t)s * 16 + t] = red[t][0] * 0.25f;
}

// ---------------- indexer scores ----------------
__global__ __launch_bounds__(256) void indexer_scores(const float* __restrict__ qi,
                                                      const float* __restrict__ ki,
                                                      const float* __restrict__ wts,
                                                      float* __restrict__ sc) {
  const int s = blockIdx.x, t = threadIdx.x;
  __shared__ float qs[16 * 128];
  __shared__ float ws[16];
  for (int i = t; i < 2048; i += 256) qs[i] = qi[(size_t)s * 2048 + i];
  if (t < 16) ws[t] = wts[(size_t)s * 16 + t];
  __syncthreads();
  const float iscale = 0.088388347648318447f;  // 128^-0.5
  for (int k = t; k <= s; k += 256) {
    const float4* kr = (const float4*)(ki + (size_t)k * 128);
    float dotn[16] = {};
#pragma unroll 8
    for (int d4 = 0; d4 < 32; d4++) {
      float4 kv4 = kr[d4];
#pragma unroll
      for (int n = 0; n < 16; n++) {
        float4 q4 = *(const float4*)(qs + n * 128 + d4 * 4);
        dotn[n] += q4.x * kv4.x + q4.y * kv4.y + q4.z * kv4.z + q4.w * kv4.w;
      }
    }
    float acc = 0.f;
#pragma unroll
    for (int n = 0; n < 16; n++) {
      float r = dotn[n] * iscale;
      acc += (r > 0.f ? r : 0.f) * ws[n];
    }
    sc[(size_t)s * 2048 + k] = acc;
  }
}

// ---------------- exact top-1024 per row (jax tie semantics) ----------------
__global__ __launch_bounds__(256) void topk_select(const float* __restrict__ sc,
                                                   int* __restrict__ sel,
                                                   int* __restrict__ selcnt) {
  const int s = blockIdx.x, t = threadIdx.x;
  if (s < TOPK_) {
    for (int k = t; k <= s; k += 256) sel[(size_t)s * TOPK_ + k] = k;
    if (t == 0) selcnt[s] = s + 1;
    return;
  }
  __shared__ unsigned keys[2048];
  __shared__ unsigned hist[256];
  __shared__ unsigned sh_prefix, sh_K, sh_cnt;
  const int L = s + 1;
  for (int k = t; k < L; k += 256) {
    unsigned u = __float_as_uint(sc[(size_t)s * 2048 + k]);
    u = (u & 0x80000000u) ? ~u : (u | 0x80000000u);
    keys[k] = u;
  }
  if (t == 0) { sh_prefix = 0u; sh_K = TOPK_; sh_cnt = 0u; }
  __syncthreads();
#pragma unroll
  for (int pass = 0; pass < 4; pass++) {
    const int shift = 24 - 8 * pass;
    const unsigned mask_hi = (pass == 0) ? 0u : (0xFFFFFFFFu << (shift + 8));
    hist[t] = 0u;
    __syncthreads();
    unsigned prefix = sh_prefix;
    for (int k = t; k < L; k += 256) {
      unsigned u = keys[k];
      if ((u & mask_hi) == prefix) atomicAdd(&hist[(u >> shift) & 255u], 1u);
    }
    __syncthreads();
    if (t == 0) {
      unsigned K = sh_K, cum = 0u;
      int b = 255;
      for (; b >= 0; b--) {
        cum += hist[b];
        if (cum >= K) break;
      }
      sh_K = K - (cum - hist[b]);
      sh_prefix = prefix | ((unsigned)b << shift);
    }
    __syncthreads();
  }
  const unsigned T = sh_prefix;
  const unsigned Keq = sh_K;
  for (int k = t; k < L; k += 256) {
    if (keys[k] > T) {
      unsigned p = atomicAdd(&sh_cnt, 1u);
      sel[(size_t)s * TOPK_ + p] = k;
    }
  }
  __syncthreads();
  if (t == 0) {
    unsigned base = sh_cnt, taken = 0u;
    for (int k = 0; k < L && taken < Keq; k++) {
      if (keys[k] == T) { sel[(size_t)s * TOPK_ + base + taken] = k; taken++; }
    }
    selcnt[s] = TOPK_;
  }
}

// ---------------- kvp (stride 640) -> kvbf bf16 (stride 576) ----------------
__global__ __launch_bounds__(256) void kv_to_bf16_pad(const float* __restrict__ kvp,
                                                      unsigned short* __restrict__ kvbf) {
  const int s = blockIdx.x, t = threadIdx.x;
  for (int c = t; c < 576; c += 256)
    kvbf[(size_t)s * 576 + c] = f2bf(kvp[(size_t)s * 640 + c]);
}

// ---------------- q_abs = (q_nope @ w_k[h]^T) * scale -> bf16 ----------------
__global__ __launch_bounds__(256) void qabs_gemm(const float* __restrict__ qb,
                                                 const float* __restrict__ w_kv_b,
                                                 unsigned short* __restrict__ qabs) {
  __shared__ float As[64][132];
  __shared__ float BsT[128][68];
  const int h = blockIdx.z;
  const int s0 = blockIdx.y * 64, c0 = blockIdx.x * 64;
  const int t = threadIdx.x;
  for (int i = t; i < 2048; i += 256) {
    int row = i >> 5, col4 = i & 31;
    *(float4*)&As[row][col4 * 4] =
        *(const float4*)(qb + (size_t)(s0 + row) * 3072 + h * 192 + col4 * 4);
  }
  for (int i = t; i < 2048; i += 256) {
    int c = i >> 5, d4 = (i & 31) * 4;
    float4 v = *(const float4*)(w_kv_b + (size_t)(c0 + c) * 4096 + h * 256 + d4);
    BsT[d4 + 0][c] = v.x;
    BsT[d4 + 1][c] = v.y;
    BsT[d4 + 2][c] = v.z;
    BsT[d4 + 3][c] = v.w;
  }
  __syncthreads();
  const int tx = t & 15, ty = t >> 4;
  float acc[4][4] = {};
  for (int k = 0; k < 128; k++) {
    float4 b = *(const float4*)&BsT[k][tx * 4];
    float a0 = As[ty * 4 + 0][k], a1 = As[ty * 4 + 1][k];
    float a2 = As[ty * 4 + 2][k], a3 = As[ty * 4 + 3][k];
    acc[0][0] += a0 * b.x; acc[0][1] += a0 * b.y; acc[0][2] += a0 * b.z; acc[0][3] += a0 * b.w;
    acc[1][0] += a1 * b.x; acc[1][1] += a1 * b.y; acc[1][2] += a1 * b.z; acc[1][3] += a1 * b.w;
    acc[2][0] += a2 * b.x; acc[2][1] += a2 * b.y; acc[2][2] += a2 * b.z; acc[2][3] += a2 * b.w;
    acc[3][0] += a3 * b.x; acc[3][1] += a3 * b.y; acc[3][2] += a3 * b.z; acc[3][3] += a3 * b.w;
  }
  const float qscale = 0.07216878364870322f;  // 192^-0.5
#pragma unroll
  for (int i = 0; i < 4; i++) {
    unsigned short* dst = qabs + (size_t)(s0 + ty * 4 + i) * 8192 + h * 512 + c0 + tx * 4;
#pragma unroll
    for (int j = 0; j < 4; j++) dst[j] = f2bf(acc[i][j] * qscale);
  }
}

// ---------------- flash attention over selected keys (absorbed) ----------------
#define KC 32
__global__ __launch_bounds__(256) void flash_attn(const unsigned short* __restrict__ qabs,
                                                  const float* __restrict__ qb,
                                                  const unsigned short* __restrict__ kvbf,
                                                  const int* __restrict__ sel,
                                                  float* __restrict__ o_c) {
  const int s = blockIdx.x, t = threadIdx.x;
  const int lane = t & 63, w = t >> 6;
  __shared__ unsigned short qs[16][584];
  __shared__ unsigned short kvs[KC][584];
  __shared__ float s_part[2][16][36];
  __shared__ float p_lds[KC][20];
  __shared__ float red[16][17];
  __shared__ float m_sh[16], l_sh[16], al_sh[16];
  const int cnt = (s < 1024) ? (s + 1) : 1024;
  const float qscale = 0.07216878364870322f;

  for (int i = t; i < 1024; i += 256) {
    int h = i >> 6, c8 = i & 63;
    *(float4*)&qs[h][c8 * 8] = *(const float4*)(qabs + (size_t)s * 8192 + h * 512 + c8 * 8);
  }
  {
    int h = t >> 4, j = (t & 15) * 4;
    float4 v = *(const float4*)(qb + (size_t)s * 3072 + h * 192 + 128 + j);
    qs[h][512 + j + 0] = f2bf(v.x * qscale);
    qs[h][512 + j + 1] = f2bf(v.y * qscale);
    qs[h][512 + j + 2] = f2bf(v.z * qscale);
    qs[h][512 + j + 3] = f2bf(v.w * qscale);
  }
  if (t < 16) { m_sh[t] = -3.0e38f; l_sh[t] = 0.f; }
  float o[8][4];
#pragma unroll
  for (int j = 0; j < 8; j++)
#pragma unroll
    for (int c = 0; c < 4; c++) o[j][c] = 0.f;
  const int hgrp = t >> 7, c4 = t & 127;
  const int h_ = t & 15, grp = t >> 4;

  for (int k0 = 0; k0 < cnt; k0 += KC) {
    __syncthreads();
    {
      int row = t >> 3, sub = t & 7;
      int gk = k0 + row;
      if (gk < cnt) {
        const unsigned short* sp = kvbf + (size_t)sel[(size_t)s * TOPK_ + gk] * 576;
#pragma unroll
        for (int j = 0; j < 9; j++)
          *(float4*)&kvs[row][(sub + 8 * j) * 8] = *(const float4*)(sp + (sub + 8 * j) * 8);
      } else {
        float4 z = make_float4(0.f, 0.f, 0.f, 0.f);
#pragma unroll
        for (int j = 0; j < 9; j++) *(float4*)&kvs[row][(sub + 8 * j) * 8] = z;
      }
    }
    __syncthreads();
    {
      const int half = w >> 1, kt = w & 1;
      const int col = lane & 15, quad = lane >> 4;
      f32x4 acc = {0.f, 0.f, 0.f, 0.f};
      const unsigned short* ap = &qs[col][half * 288 + quad * 8];
      const unsigned short* bp = &kvs[kt * 16 + col][half * 288 + quad * 8];
#pragma unroll
      for (int kk = 0; kk < 9; kk++) {
        bf16x8 a = *(const bf16x8*)(ap + kk * 32);
        bf16x8 b = *(const bf16x8*)(bp + kk * 32);
        acc = __builtin_amdgcn_mfma_f32_16x16x32_bf16(a, b, acc, 0, 0, 0);
      }
#pragma unroll
      for (int r = 0; r < 4; r++) s_part[half][quad * 4 + r][kt * 16 + col] = acc[r];
    }
    __syncthreads();
    float v0, v1;
    {
      int kk0 = grp * 2, kk1 = grp * 2 + 1;
      v0 = (k0 + kk0 < cnt) ? (s_part[0][h_][kk0] + s_part[1][h_][kk0]) : -3.0e38f;
      v1 = (k0 + kk1 < cnt) ? (s_part[0][h_][kk1] + s_part[1][h_][kk1]) : -3.0e38f;
      red[h_][grp] = fmaxf(v0, v1);
    }
    __syncthreads();
    if (t < 16) {
      float mc = red[t][0];
#pragma unroll
      for (int g = 1; g < 16; g++) mc = fmaxf(mc, red[t][g]);
      float mo = m_sh[t];
      float mn = fmaxf(mo, mc);
      m_sh[t] = mn;
      al_sh[t] = __expf(mo - mn);
    }
    __syncthreads();
    {
      float mm = m_sh[h_];
      float e0 = __expf(v0 - mm);
      float e1 = __expf(v1 - mm);
      p_lds[grp * 2][h_] = e0;
      p_lds[grp * 2 + 1][h_] = e1;
      red[h_][grp] = e0 + e1;
    }
    __syncthreads();
    if (t < 16) {
      float sl = 0.f;
#pragma unroll
      for (int g = 0; g < 16; g++) sl += red[t][g];
      l_sh[t] = l_sh[t] * al_sh[t] + sl;
    }
    __syncthreads();
    {
      float a_[8];
#pragma unroll
      for (int j = 0; j < 8; j++) a_[j] = al_sh[hgrp * 8 + j];
#pragma unroll
      for (int j = 0; j < 8; j++) {
        o[j][0] *= a_[j]; o[j][1] *= a_[j]; o[j][2] *= a_[j]; o[j][3] *= a_[j];
      }
      for (int k = 0; k < KC; k++) {
        uint2 kk = *(const uint2*)&kvs[k][c4 * 4];
        float kv0 = __uint_as_float(kk.x << 16);
        float kv1 = __uint_as_float(kk.x & 0xFFFF0000u);
        float kv2 = __uint_as_float(kk.y << 16);
        float kv3 = __uint_as_float(kk.y & 0xFFFF0000u);
        float4 p0 = *(const float4*)&p_lds[k][hgrp * 8];
        float4 p1 = *(const float4*)&p_lds[k][hgrp * 8 + 4];
        float pj[8] = {p0.x, p0.y, p0.z, p0.w, p1.x, p1.y, p1.z, p1.w};
#pragma unroll
        for (int j = 0; j < 8; j++) {
          o[j][0] += pj[j] * kv0;
          o[j][1] += pj[j] * kv1;
          o[j][2] += pj[j] * kv2;
          o[j][3] += pj[j] * kv3;
        }
      }
    }
  }
  __syncthreads();
  if (t < 16) l_sh[t] = 1.0f / l_sh[t];
  __syncthreads();
#pragma unroll
  for (int j = 0; j < 8; j++) {
    float li = l_sh[hgrp * 8 + j];
    float4 vv = make_float4(o[j][0] * li, o[j][1] * li, o[j][2] * li, o[j][3] * li);
    *(float4*)(o_c + (size_t)s * 8192 + (hgrp * 8 + j) * 512 + c4 * 4) = vv;
  }
}

// ---------------- launch ----------------
extern "C" void kernel_launch(void* const* d_in, const int* in_sizes, int n_in,
                              void* d_out, int out_size, void* d_ws, size_t ws_size,
                              hipStream_t stream) {
  const float* hs         = (const float*)d_in[0];
  const float* cosp       = (const float*)d_in[1];
  const float* sinp       = (const float*)d_in[2];
  const float* w_q_a      = (const float*)d_in[3];
  const float* q_a_ln_w   = (const float*)d_in[4];
  const float* w_q_b      = (const float*)d_in[5];
  const float* w_kv_a     = (const float*)d_in[6];
  const float* kv_a_ln_w  = (const float*)d_in[7];
  const float* w_kv_b     = (const float*)d_in[8];
  const float* w_o        = (const float*)d_in[9];
  const float* idx_wq_b   = (const float*)d_in[10];
  const float* idx_wk     = (const float*)d_in[11];
  const float* idx_k_ln_w = (const float*)d_in[12];
  const float* idx_k_ln_b = (const float*)d_in[13];
  const float* idx_w_proj = (const float*)d_in[14];
  float* out = (float*)d_out;

  float* ws = (float*)d_ws;
  float* cq   = ws;                       // 3,145,728 f  (later aliased by attnbbf)
  float* qb   = ws + 3145728;             // 6,291,456 f
  float* kvp  = ws + 9437184;             // 2048x640 = 1,310,720 f
  float* qi   = ws + 10747904;            // 4,194,304 f ┐ qabs aliases qi+isc
  float* isc  = ws + 14942208;            // 4,194,304 f ┘
  float* ki   = ws + 19136512;            // 262,144 f
  float* wts  = ws + 19398656;            // 32,768 f
  float* o_c  = ws + 19431424;            // 16,777,216 f
  unsigned short* hsbf = (unsigned short*)(ws + 36208640);   // 8,388,608 sh
  unsigned short* cqbf = (unsigned short*)(ws + 40402944);   // 3,145,728 sh
  unsigned short* kvbf = (unsigned short*)(ws + 41975808);   // 1,179,648 sh
  unsigned short* wT   = (unsigned short*)(ws + 42565632);   // 8,388,608 sh scratch
  int* sel    = (int*)(ws + 46759936);    // 2,097,152 int
  int* selcnt = sel + 2097152;
  unsigned short* qabs   = (unsigned short*)qi;   // 16,777,216 sh over qi+isc
  unsigned short* attnbbf = (unsigned short*)cq;  // 4,194,304 sh over cq

  // ---- casts ----
  cast_bf16<<<4096, 256, 0, stream>>>(hs, hsbf);  // 8.4M elems

  // ---- cq = hs @ w_q_a ; rmsnorm (+bf16) ----
  transpose_cast<<<dim3(48, 64), 256, 0, stream>>>(w_q_a, wT, 4096, 1536);
  gemm_bf16<<<dim3(12, 16), 256, 0, stream>>>(hsbf, wT, cq, 4096, 1536);
  rmsnorm_bf16_kernel<<<2048, 256, 0, stream>>>(cq, q_a_ln_w, cqbf, 1536, 1536);

  // ---- indexer path first (so qi/isc die before qabs aliases them) ----
  transpose_cast<<<dim3(64, 24), 256, 0, stream>>>(idx_wq_b, wT, 1536, 2048);
  gemm_bf16<<<dim3(16, 16), 256, 0, stream>>>(cqbf, wT, qi, 1536, 2048);
  rope_qi_nonint<<<4096, 256, 0, stream>>>(qi, cosp, sinp);
  gemm_f32<<<dim3(2, 32), 256, 0, stream>>>(hs, idx_wk, ki, 4096, 4096, 128, 128);
  layernorm128_kernel<<<2048, 128, 0, stream>>>(ki, idx_k_ln_w, idx_k_ln_b);
  rope_ki_nonint<<<256, 256, 0, stream>>>(ki, cosp, sinp);
  wts_kernel<<<2048, 256, 0, stream>>>(hs, idx_w_proj, wts);
  indexer_scores<<<2048, 256, 0, stream>>>(qi, ki, wts, isc);
  topk_select<<<2048, 256, 0, stream>>>(isc, sel, selcnt);

  // ---- qb = cq @ w_q_b ; rope ----
  transpose_cast<<<dim3(96, 24), 256, 0, stream>>>(w_q_b, wT, 1536, 3072);
  gemm_bf16<<<dim3(24, 16), 256, 0, stream>>>(cqbf, wT, qb, 1536, 3072);
  rope_q_inter<<<4096, 256, 0, stream>>>(qb, cosp, sinp);

  // ---- kv = hs @ w_kv_a (padded N=640) ; rmsnorm ; rope ; bf16 ----
  transpose_cast<<<dim3(20, 64), 256, 0, stream>>>(w_kv_a, wT, 4096, 576);
  gemm_bf16<<<dim3(5, 16), 256, 0, stream>>>(hsbf, wT, kvp, 4096, 640);
  rmsnorm_kernel<<<2048, 256, 0, stream>>>(kvp, kv_a_ln_w, 512, 640);
  rope_k_inter<<<256, 256, 0, stream>>>(kvp, cosp, sinp, 640);
  kv_to_bf16_pad<<<2048, 256, 0, stream>>>(kvp, kvbf);

  // ---- q_abs (absorbed q, bf16, pre-scaled); qabs aliases qi+isc (dead) ----
  qabs_gemm<<<dim3(8, 32, 16), 256, 0, stream>>>(qb, w_kv_b, qabs);

  // ---- flash attention ----
  flash_attn<<<2048, 256, 0, stream>>>(qabs, qb, kvbf, sel, o_c);

  // ---- attn_out[s,h,:] = o_c[s,h,:] @ w_v[h] -> bf16 (aliases cq, dead) ----
  gemm_f32_z_bf<<<dim3(2, 32, 16), 256, 0, stream>>>(o_c, w_kv_b + 128, attnbbf,
                                                     512, 8192, 4096, 2048, 512, 256, 128);

  // ---- out = attn_out @ w_o ----
  transpose_cast<<<dim3(128, 32), 256, 0, stream>>>(w_o, wT, 2048, 4096);
  gemm_bf16<<<dim3(32, 16), 256, 0, stream>>>(attnbbf, wT, out, 2048, 4096);
}

// Round 5
// 1239.361 us; speedup vs baseline: 8.0668x; 1.5556x over previous
//
#include <hip/hip_runtime.h>
#include <math.h>

// Shapes (B=1 throughout)
#define S_LEN 2048
#define D_MODEL 4096
#define NH 16
#define TOPK_ 1024

typedef float f32x4 __attribute__((ext_vector_type(4)));
typedef short bf16x8 __attribute__((ext_vector_type(8)));

__device__ __forceinline__ unsigned short f2bf(float f) {
  unsigned u = __float_as_uint(f);
  u += 0x7fffu + ((u >> 16) & 1u);  // RNE
  return (unsigned short)(u >> 16);
}

// ---------------- generalized bf16 MFMA GEMM: C[M,N] = A[M,K] @ Bt[N,K]^T ----------------
// Tile 128x128, BK=32, 256 threads. M%128==0, N%128==0, K%32==0.
#define LDSW 40
__global__ __launch_bounds__(256) void gemm_bf16x(const unsigned short* __restrict__ A,
                                                  const unsigned short* __restrict__ Bt,
                                                  float* __restrict__ C,
                                                  int K, int lda, int ldb, int ldc,
                                                  int za, int zb, int zc) {
  A += (size_t)blockIdx.z * za;
  Bt += (size_t)blockIdx.z * zb;
  C += (size_t)blockIdx.z * zc;
  __shared__ unsigned short As[128 * LDSW];
  __shared__ unsigned short Bs[128 * LDSW];
  const int t = threadIdx.x, lane = t & 63, w = t >> 6;
  const int m0 = blockIdx.y * 128, n0 = blockIdx.x * 128;
  const int mb = (w & 1) * 64, nb = (w >> 1) * 64;
  const int fr = lane & 15, fq = lane >> 4;
  f32x4 acc[4][4];
#pragma unroll
  for (int i = 0; i < 4; i++)
#pragma unroll
    for (int j = 0; j < 4; j++) acc[i][j] = (f32x4){0.f, 0.f, 0.f, 0.f};
  const int srow0 = t >> 2, ssub = (t & 3) * 8;
  const int srow1 = (t + 256) >> 2;
  for (int k0 = 0; k0 < K; k0 += 32) {
    __syncthreads();
    {
      float4 a0 = *(const float4*)(A + (size_t)(m0 + srow0) * lda + k0 + ssub);
      float4 a1 = *(const float4*)(A + (size_t)(m0 + srow1) * lda + k0 + ssub);
      float4 b0 = *(const float4*)(Bt + (size_t)(n0 + srow0) * ldb + k0 + ssub);
      float4 b1 = *(const float4*)(Bt + (size_t)(n0 + srow1) * ldb + k0 + ssub);
      *(float4*)&As[srow0 * LDSW + ssub] = a0;
      *(float4*)&As[srow1 * LDSW + ssub] = a1;
      *(float4*)&Bs[srow0 * LDSW + ssub] = b0;
      *(float4*)&Bs[srow1 * LDSW + ssub] = b1;
    }
    __syncthreads();
    bf16x8 af[4], bfr[4];
#pragma unroll
    for (int mt = 0; mt < 4; mt++) af[mt] = *(const bf16x8*)&As[(mb + mt * 16 + fr) * LDSW + fq * 8];
#pragma unroll
    for (int nt = 0; nt < 4; nt++) bfr[nt] = *(const bf16x8*)&Bs[(nb + nt * 16 + fr) * LDSW + fq * 8];
#pragma unroll
    for (int mt = 0; mt < 4; mt++)
#pragma unroll
      for (int nt = 0; nt < 4; nt++)
        acc[mt][nt] = __builtin_amdgcn_mfma_f32_16x16x32_bf16(af[mt], bfr[nt], acc[mt][nt], 0, 0, 0);
  }
#pragma unroll
  for (int mt = 0; mt < 4; mt++) {
#pragma unroll
    for (int r = 0; r < 4; r++) {
      int row = m0 + mb + mt * 16 + fq * 4 + r;
      float* cp = C + (size_t)row * ldc + n0 + nb + fr;
#pragma unroll
      for (int nt = 0; nt < 4; nt++) cp[nt * 16] = acc[mt][nt][r];
    }
  }
}

// same, bf16 output with scale
__global__ __launch_bounds__(256) void gemm_bf16x_bf(const unsigned short* __restrict__ A,
                                                     const unsigned short* __restrict__ Bt,
                                                     unsigned short* __restrict__ C,
                                                     int K, int lda, int ldb, int ldc,
                                                     int za, int zb, int zc, float scale) {
  A += (size_t)blockIdx.z * za;
  Bt += (size_t)blockIdx.z * zb;
  C += (size_t)blockIdx.z * zc;
  __shared__ unsigned short As[128 * LDSW];
  __shared__ unsigned short Bs[128 * LDSW];
  const int t = threadIdx.x, lane = t & 63, w = t >> 6;
  const int m0 = blockIdx.y * 128, n0 = blockIdx.x * 128;
  const int mb = (w & 1) * 64, nb = (w >> 1) * 64;
  const int fr = lane & 15, fq = lane >> 4;
  f32x4 acc[4][4];
#pragma unroll
  for (int i = 0; i < 4; i++)
#pragma unroll
    for (int j = 0; j < 4; j++) acc[i][j] = (f32x4){0.f, 0.f, 0.f, 0.f};
  const int srow0 = t >> 2, ssub = (t & 3) * 8;
  const int srow1 = (t + 256) >> 2;
  for (int k0 = 0; k0 < K; k0 += 32) {
    __syncthreads();
    {
      float4 a0 = *(const float4*)(A + (size_t)(m0 + srow0) * lda + k0 + ssub);
      float4 a1 = *(const float4*)(A + (size_t)(m0 + srow1) * lda + k0 + ssub);
      float4 b0 = *(const float4*)(Bt + (size_t)(n0 + srow0) * ldb + k0 + ssub);
      float4 b1 = *(const float4*)(Bt + (size_t)(n0 + srow1) * ldb + k0 + ssub);
      *(float4*)&As[srow0 * LDSW + ssub] = a0;
      *(float4*)&As[srow1 * LDSW + ssub] = a1;
      *(float4*)&Bs[srow0 * LDSW + ssub] = b0;
      *(float4*)&Bs[srow1 * LDSW + ssub] = b1;
    }
    __syncthreads();
    bf16x8 af[4], bfr[4];
#pragma unroll
    for (int mt = 0; mt < 4; mt++) af[mt] = *(const bf16x8*)&As[(mb + mt * 16 + fr) * LDSW + fq * 8];
#pragma unroll
    for (int nt = 0; nt < 4; nt++) bfr[nt] = *(const bf16x8*)&Bs[(nb + nt * 16 + fr) * LDSW + fq * 8];
#pragma unroll
    for (int mt = 0; mt < 4; mt++)
#pragma unroll
      for (int nt = 0; nt < 4; nt++)
        acc[mt][nt] = __builtin_amdgcn_mfma_f32_16x16x32_bf16(af[mt], bfr[nt], acc[mt][nt], 0, 0, 0);
  }
#pragma unroll
  for (int mt = 0; mt < 4; mt++) {
#pragma unroll
    for (int r = 0; r < 4; r++) {
      int row = m0 + mb + mt * 16 + fq * 4 + r;
      unsigned short* cp = C + (size_t)row * ldc + n0 + nb + fr;
#pragma unroll
      for (int nt = 0; nt < 4; nt++) cp[nt * 16] = f2bf(acc[mt][nt][r] * scale);
    }
  }
}

// ---------------- cast fp32 -> bf16 (8 elems/thread) ----------------
__global__ __launch_bounds__(256) void cast_bf16(const float* __restrict__ in,
                                                 unsigned short* __restrict__ out) {
  size_t i = (size_t)(blockIdx.x * 256 + threadIdx.x) * 8;
  float4 v0 = *(const float4*)(in + i);
  float4 v1 = *(const float4*)(in + i + 4);
  unsigned short tmp[8] = {f2bf(v0.x), f2bf(v0.y), f2bf(v0.z), f2bf(v0.w),
                           f2bf(v1.x), f2bf(v1.y), f2bf(v1.z), f2bf(v1.w)};
  *(float4*)(out + i) = *(float4*)tmp;
}

// ---------------- transpose+cast: in fp32 [K,N] -> out bf16 [Npad,K] ----------------
__global__ __launch_bounds__(256) void transpose_cast(const float* __restrict__ in,
                                                      unsigned short* __restrict__ out,
                                                      int K, int N) {
  __shared__ float buf[64][33];
  const int k0 = blockIdx.y * 64, n0 = blockIdx.x * 32;
  const int t = threadIdx.x;
  const bool valid = (n0 < N);
  if (valid) {
#pragma unroll
    for (int i = 0; i < 2; i++) {
      int c = i * 256 + t;
      int kk = c >> 3, nn = (c & 7) * 4;
      float4 v = *(const float4*)(in + (size_t)(k0 + kk) * N + n0 + nn);
      buf[kk][nn] = v.x; buf[kk][nn + 1] = v.y; buf[kk][nn + 2] = v.z; buf[kk][nn + 3] = v.w;
    }
  }
  __syncthreads();
  const int n = t >> 3, k8 = (t & 7) * 8;
  unsigned short tmp[8];
#pragma unroll
  for (int j = 0; j < 8; j++) tmp[j] = valid ? f2bf(buf[k8 + j][n]) : (unsigned short)0;
  *(float4*)(out + (size_t)(n0 + n) * K + k0 + k8) = *(float4*)tmp;
}

// ---------------- transpose w_v slice: wvT[h][d][c] = wkvbbf[c][h*256+128+d] ----------------
__global__ __launch_bounds__(256) void transpose_wv(const unsigned short* __restrict__ wkvbbf,
                                                    unsigned short* __restrict__ wvT) {
  __shared__ unsigned short tile[128][136];
  const int c0 = blockIdx.x * 128, h = blockIdx.y;
  const int t = threadIdx.x;
  for (int i = t; i < 128 * 16; i += 256) {
    int c = i >> 4, sub = (i & 15) * 8;
    *(float4*)&tile[c][sub] = *(const float4*)(wkvbbf + (size_t)(c0 + c) * 4096 + h * 256 + 128 + sub);
  }
  __syncthreads();
  for (int i = t; i < 128 * 16; i += 256) {
    int d = i >> 4, cs = (i & 15) * 8;
    unsigned short tmp[8];
#pragma unroll
    for (int j = 0; j < 8; j++) tmp[j] = tile[cs + j][d];
    *(float4*)(wvT + (size_t)h * 65536 + (size_t)d * 512 + c0 + cs) = *(float4*)tmp;
  }
}

// ---------------- RMSNorm in place ----------------
__global__ __launch_bounds__(256) void rmsnorm_kernel(float* __restrict__ x,
                                                      const float* __restrict__ w,
                                                      int ncol, int stride) {
  const int s = blockIdx.x, t = threadIdx.x;
  float* row = x + (size_t)s * stride;
  float ss = 0.f;
  for (int d = t; d < ncol; d += 256) { float v = row[d]; ss += v * v; }
  __shared__ float red[256];
  red[t] = ss;
  __syncthreads();
  for (int o = 128; o > 0; o >>= 1) { if (t < o) red[t] += red[t + o]; __syncthreads(); }
  float r = 1.0f / sqrtf(red[0] / (float)ncol + 1e-6f);
  for (int d = t; d < ncol; d += 256) row[d] = row[d] * r * w[d];
}

// RMSNorm in place + bf16 copy out
__global__ __launch_bounds__(256) void rmsnorm_bf16_kernel(float* __restrict__ x,
                                                           const float* __restrict__ w,
                                                           unsigned short* __restrict__ xbf,
                                                           int ncol, int stride) {
  const int s = blockIdx.x, t = threadIdx.x;
  float* row = x + (size_t)s * stride;
  float ss = 0.f;
  for (int d = t; d < ncol; d += 256) { float v = row[d]; ss += v * v; }
  __shared__ float red[256];
  red[t] = ss;
  __syncthreads();
  for (int o = 128; o > 0; o >>= 1) { if (t < o) red[t] += red[t + o]; __syncthreads(); }
  float r = 1.0f / sqrtf(red[0] / (float)ncol + 1e-6f);
  for (int d = t; d < ncol; d += 256) {
    float v = row[d] * r * w[d];
    row[d] = v;
    xbf[(size_t)s * ncol + d] = f2bf(v);
  }
}

// ---------------- LayerNorm in place over 128 cols ----------------
__global__ __launch_bounds__(128) void layernorm128_kernel(float* __restrict__ x,
                                                           const float* __restrict__ w,
                                                           const float* __restrict__ b) {
  const int s = blockIdx.x, t = threadIdx.x;
  float* row = x + (size_t)s * 128;
  __shared__ float red[128];
  float v = row[t];
  red[t] = v;
  __syncthreads();
  for (int o = 64; o > 0; o >>= 1) { if (t < o) red[t] += red[t + o]; __syncthreads(); }
  float mu = red[0] / 128.f;
  __syncthreads();
  float d = v - mu;
  red[t] = d * d;
  __syncthreads();
  for (int o = 64; o > 0; o >>= 1) { if (t < o) red[t] += red[t + o]; __syncthreads(); }
  float var = red[0] / 128.f;
  row[t] = d * (1.0f / sqrtf(var + 1e-5f)) * w[t] + b[t];
}

// ---------------- RoPE kernels ----------------
__global__ __launch_bounds__(256) void rope_q_inter(float* __restrict__ q,
                                                    const float* __restrict__ cosp,
                                                    const float* __restrict__ sinp) {
  int id = blockIdx.x * 256 + threadIdx.x;
  int s = id >> 9, r = id & 511, h = r >> 5, j = r & 31;
  float c = cosp[s * 32 + j], sn = sinp[s * 32 + j];
  float* base = q + (size_t)s * (NH * 192) + h * 192 + 128 + 2 * j;
  float x0 = base[0], x1 = base[1];
  base[0] = x0 * c - x1 * sn;
  base[1] = x0 * sn + x1 * c;
}

__global__ __launch_bounds__(256) void rope_k_inter(float* __restrict__ kv,
                                                    const float* __restrict__ cosp,
                                                    const float* __restrict__ sinp,
                                                    int stride) {
  int id = blockIdx.x * 256 + threadIdx.x;
  int s = id >> 5, j = id & 31;
  float c = cosp[s * 32 + j], sn = sinp[s * 32 + j];
  float* base = kv + (size_t)s * stride + 512 + 2 * j;
  float x0 = base[0], x1 = base[1];
  base[0] = x0 * c - x1 * sn;
  base[1] = x0 * sn + x1 * c;
}

__global__ __launch_bounds__(256) void rope_qi_nonint(float* __restrict__ qi,
                                                      const float* __restrict__ cosp,
                                                      const float* __restrict__ sinp) {
  int id = blockIdx.x * 256 + threadIdx.x;
  int s = id >> 9, r = id & 511, n = r >> 5, j = r & 31;
  float c = cosp[s * 32 + j], sn = sinp[s * 32 + j];
  float* base = qi + (size_t)s * 2048 + n * 128;
  float xr = base[j], xi = base[j + 32];
  base[j] = xr * c - xi * sn;
  base[j + 32] = xr * sn + xi * c;
}

__global__ __launch_bounds__(256) void rope_ki_nonint(float* __restrict__ ki,
                                                      const float* __restrict__ cosp,
                                                      const float* __restrict__ sinp) {
  int id = blockIdx.x * 256 + threadIdx.x;
  int s = id >> 5, j = id & 31;
  float c = cosp[s * 32 + j], sn = sinp[s * 32 + j];
  float* base = ki + (size_t)s * 128;
  float xr = base[j], xi = base[j + 32];
  base[j] = xr * c - xi * sn;
  base[j + 32] = xr * sn + xi * c;
}

// ---------------- wts = hidden @ idx_w_proj * (0.25 * 128^-0.5)  (iscale folded) ----------------
__global__ __launch_bounds__(256) void wts_kernel(const float* __restrict__ hs,
                                                  const float* __restrict__ wp,
                                                  float* __restrict__ wts) {
  const int s = blockIdx.x, t = threadIdx.x;
  float acc[16] = {};
  for (int d = t; d < D_MODEL; d += 256) {
    float h = hs[(size_t)s * D_MODEL + d];
    const float* w = wp + (size_t)d * 16;
#pragma unroll
    for (int n = 0; n < 16; n++) acc[n] += h * w[n];
  }
  __shared__ float red[16][256];
#pragma unroll
  for (int n = 0; n < 16; n++) red[n][t] = acc[n];
  __syncthreads();
  for (int o = 128; o > 0; o >>= 1) {
    if (t < o) {
#pragma unroll
      for (int n = 0; n < 16; n++) red[n][t] += red[n][t + o];
    }
    __syncthreads();
  }
  if (t < 16) wts[(size_t)s * 16 + t] = red[t][0] * 0.022097086912079613f;
}

// ---------------- indexer scores via MFMA, 64x64 lower-tri tiles ----------------
__global__ __launch_bounds__(256) void indexer_mfma(const unsigned short* __restrict__ qibf,
                                                    const unsigned short* __restrict__ kibf,
                                                    const float* __restrict__ wts,
                                                    float* __restrict__ isc) {
  __shared__ unsigned short kis[64 * 136];
  __shared__ unsigned short qis[64 * 136];
  __shared__ float wt_s[64 * 16];
  const int t = threadIdx.x, lane = t & 63, w = t >> 6;
  const int ln = lane & 15, quad = lane >> 4;
  int b = blockIdx.x;
  int qt = (int)((sqrtf(8.0f * b + 1.0f) - 1.0f) * 0.5f);
  while ((qt + 1) * (qt + 2) / 2 <= b) qt++;
  while (qt * (qt + 1) / 2 > b) qt--;
  const int kt = b - qt * (qt + 1) / 2;
  const int q0 = qt * 64, k0 = kt * 64;
#pragma unroll
  for (int p = 0; p < 4; p++) {
    int i = t + p * 256;
    int row = i >> 4, sub = (i & 15) * 8;
    *(float4*)&kis[row * 136 + sub] = *(const float4*)(kibf + (size_t)(k0 + row) * 128 + sub);
  }
  {
    int rw = t >> 2, n4 = (t & 3) * 4;
    *(float4*)&wt_s[rw * 16 + n4] = *(const float4*)(wts + (size_t)(q0 + rw) * 16 + n4);
  }
  __syncthreads();
  bf16x8 kb[4][4];
#pragma unroll
  for (int nt = 0; nt < 4; nt++)
#pragma unroll
    for (int kk = 0; kk < 4; kk++)
      kb[nt][kk] = *(const bf16x8*)&kis[(nt * 16 + ln) * 136 + kk * 32 + quad * 8];
  f32x4 iacc[4];
#pragma unroll
  for (int nt = 0; nt < 4; nt++) iacc[nt] = (f32x4){0.f, 0.f, 0.f, 0.f};

  for (int n = 0; n < 16; n++) {
    __syncthreads();
#pragma unroll
    for (int p = 0; p < 4; p++) {
      int i = t + p * 256;
      int row = i >> 4, sub = (i & 15) * 8;
      *(float4*)&qis[row * 136 + sub] =
          *(const float4*)(qibf + (size_t)(q0 + row) * 2048 + n * 128 + sub);
    }
    __syncthreads();
    bf16x8 qa[4];
#pragma unroll
    for (int kk = 0; kk < 4; kk++)
      qa[kk] = *(const bf16x8*)&qis[(w * 16 + ln) * 136 + kk * 32 + quad * 8];
    float wv0 = wt_s[(w * 16 + quad * 4 + 0) * 16 + n];
    float wv1 = wt_s[(w * 16 + quad * 4 + 1) * 16 + n];
    float wv2 = wt_s[(w * 16 + quad * 4 + 2) * 16 + n];
    float wv3 = wt_s[(w * 16 + quad * 4 + 3) * 16 + n];
#pragma unroll
    for (int nt = 0; nt < 4; nt++) {
      f32x4 sacc = (f32x4){0.f, 0.f, 0.f, 0.f};
#pragma unroll
      for (int kk = 0; kk < 4; kk++)
        sacc = __builtin_amdgcn_mfma_f32_16x16x32_bf16(qa[kk], kb[nt][kk], sacc, 0, 0, 0);
      iacc[nt][0] += fmaxf(sacc[0], 0.f) * wv0;
      iacc[nt][1] += fmaxf(sacc[1], 0.f) * wv1;
      iacc[nt][2] += fmaxf(sacc[2], 0.f) * wv2;
      iacc[nt][3] += fmaxf(sacc[3], 0.f) * wv3;
    }
  }
#pragma unroll
  for (int nt = 0; nt < 4; nt++) {
#pragma unroll
    for (int r = 0; r < 4; r++) {
      int qg = q0 + w * 16 + quad * 4 + r;
      int kg = k0 + nt * 16 + ln;
      isc[(size_t)qg * 2048 + kg] = (kg <= qg) ? iacc[nt][r] : -1.0e30f;
    }
  }
}

// ---------------- exact top-1024 per row (jax tie semantics) ----------------
__global__ __launch_bounds__(256) void topk_select(const float* __restrict__ sc,
                                                   int* __restrict__ sel,
                                                   int* __restrict__ selcnt) {
  const int s = blockIdx.x, t = threadIdx.x;
  if (s < TOPK_) {
    for (int k = t; k <= s; k += 256) sel[(size_t)s * TOPK_ + k] = k;
    if (t == 0) selcnt[s] = s + 1;
    return;
  }
  __shared__ unsigned keys[2048];
  __shared__ unsigned hist[256];
  __shared__ unsigned sh_prefix, sh_K, sh_cnt;
  const int L = s + 1;
  for (int k = t; k < L; k += 256) {
    unsigned u = __float_as_uint(sc[(size_t)s * 2048 + k]);
    u = (u & 0x80000000u) ? ~u : (u | 0x80000000u);
    keys[k] = u;
  }
  if (t == 0) { sh_prefix = 0u; sh_K = TOPK_; sh_cnt = 0u; }
  __syncthreads();
#pragma unroll
  for (int pass = 0; pass < 4; pass++) {
    const int shift = 24 - 8 * pass;
    const unsigned mask_hi = (pass == 0) ? 0u : (0xFFFFFFFFu << (shift + 8));
    hist[t] = 0u;
    __syncthreads();
    unsigned prefix = sh_prefix;
    for (int k = t; k < L; k += 256) {
      unsigned u = keys[k];
      if ((u & mask_hi) == prefix) atomicAdd(&hist[(u >> shift) & 255u], 1u);
    }
    __syncthreads();
    if (t == 0) {
      unsigned K = sh_K, cum = 0u;
      int b = 255;
      for (; b >= 0; b--) {
        cum += hist[b];
        if (cum >= K) break;
      }
      sh_K = K - (cum - hist[b]);
      sh_prefix = prefix | ((unsigned)b << shift);
    }
    __syncthreads();
  }
  const unsigned T = sh_prefix;
  const unsigned Keq = sh_K;
  for (int k = t; k < L; k += 256) {
    if (keys[k] > T) {
      unsigned p = atomicAdd(&sh_cnt, 1u);
      sel[(size_t)s * TOPK_ + p] = k;
    }
  }
  __syncthreads();
  if (t == 0) {
    unsigned base = sh_cnt, taken = 0u;
    for (int k = 0; k < L && taken < Keq; k++) {
      if (keys[k] == T) { sel[(size_t)s * TOPK_ + base + taken] = k; taken++; }
    }
    selcnt[s] = TOPK_;
  }
}

// ---------------- kvp (stride 640) -> kvbf bf16 (stride 576) ----------------
__global__ __launch_bounds__(256) void kv_to_bf16_pad(const float* __restrict__ kvp,
                                                      unsigned short* __restrict__ kvbf) {
  const int s = blockIdx.x, t = threadIdx.x;
  for (int c = t; c < 576; c += 256)
    kvbf[(size_t)s * 576 + c] = f2bf(kvp[(size_t)s * 640 + c]);
}

// ---------------- qfull rope fill: qfull[s][h*576+512+2j..] = bf16(rope(qb)*qscale) ----------------
__global__ __launch_bounds__(256) void qfull_rope(const float* __restrict__ qb,
                                                  unsigned short* __restrict__ qfull) {
  int id = blockIdx.x * 256 + threadIdx.x;  // S*16*32
  int s = id >> 9, r = id & 511, h = r >> 5, j = r & 31;
  const float qscale = 0.07216878364870322f;
  const float* src = qb + (size_t)s * 3072 + h * 192 + 128 + 2 * j;
  unsigned pk = (unsigned)f2bf(src[0] * qscale) | ((unsigned)f2bf(src[1] * qscale) << 16);
  *(unsigned*)(qfull + (size_t)s * 9216 + h * 576 + 512 + 2 * j) = pk;
}

// ---------------- flash attention v2: c-pair-major kv LDS, MFMA QK + MFMA PV ----------------
#define KC 32
__global__ __launch_bounds__(256) void flash_attn2(const unsigned short* __restrict__ qfull,
                                                   const unsigned short* __restrict__ kvbf,
                                                   const int* __restrict__ sel,
                                                   unsigned short* __restrict__ o_c) {
  const int s = blockIdx.x, t = threadIdx.x;
  const int lane = t & 63, w = t >> 6;
  const int half = w >> 1, kt = w & 1;
  const int ln = lane & 15, quad = lane >> 4;
  __shared__ unsigned kvt2[288 * 36];        // [c2][key] dword = 2 bf16 (c even, c odd)
  __shared__ float s_part[2][16][36];
  __shared__ unsigned short p_bf[16][40];
  __shared__ float red[16][17];
  __shared__ float m_sh[16], l_sh[16], al_sh[16];
  const int cnt = (s < 1024) ? (s + 1) : 1024;

  bf16x8 qa[9];
  {
    const unsigned short* qrow = qfull + (size_t)s * 9216 + ln * 576 + half * 288 + quad * 8;
#pragma unroll
    for (int kk = 0; kk < 9; kk++) qa[kk] = *(const bf16x8*)(qrow + kk * 32);
  }
  if (t < 16) { m_sh[t] = -3.0e38f; l_sh[t] = 0.f; }
  f32x4 o[8];
#pragma unroll
  for (int i = 0; i < 8; i++) o[i] = (f32x4){0.f, 0.f, 0.f, 0.f};
  const int h_ = t & 15, grp = t >> 4;
  const int skey = t >> 3, ssub = t & 7;

  for (int k0 = 0; k0 < cnt; k0 += KC) {
    __syncthreads();
    {
      int gk = k0 + skey;
      if (gk < cnt) {
        const unsigned short* sp = kvbf + (size_t)sel[(size_t)s * TOPK_ + gk] * 576;
#pragma unroll
        for (int j = 0; j < 9; j++) {
          int c0 = (ssub + 8 * j) * 8;
          float4 v = *(const float4*)(sp + c0);
          const unsigned* pv = (const unsigned*)&v;
          int base = (c0 >> 1) * 36 + skey;
          kvt2[base] = pv[0];
          kvt2[base + 36] = pv[1];
          kvt2[base + 72] = pv[2];
          kvt2[base + 108] = pv[3];
        }
      } else {
#pragma unroll
        for (int j = 0; j < 9; j++) {
          int base = ((ssub + 8 * j) * 4) * 36 + skey;
          kvt2[base] = 0u; kvt2[base + 36] = 0u; kvt2[base + 72] = 0u; kvt2[base + 108] = 0u;
        }
      }
    }
    __syncthreads();
    // QK: wave covers K-half `half`, key-tile kt
    {
      f32x4 sacc = (f32x4){0.f, 0.f, 0.f, 0.f};
      const int keyi = kt * 16 + ln;
#pragma unroll
      for (int kk = 0; kk < 9; kk++) {
        int c2b = half * 144 + kk * 16 + quad * 4;
        unsigned bw[4];
        bw[0] = kvt2[c2b * 36 + keyi];
        bw[1] = kvt2[(c2b + 1) * 36 + keyi];
        bw[2] = kvt2[(c2b + 2) * 36 + keyi];
        bw[3] = kvt2[(c2b + 3) * 36 + keyi];
        sacc = __builtin_amdgcn_mfma_f32_16x16x32_bf16(qa[kk], *(const bf16x8*)bw, sacc, 0, 0, 0);
      }
#pragma unroll
      for (int r = 0; r < 4; r++) s_part[half][quad * 4 + r][kt * 16 + ln] = sacc[r];
    }
    __syncthreads();
    float v0, v1;
    {
      int kk0 = grp * 2, kk1 = kk0 + 1;
      v0 = (k0 + kk0 < cnt) ? (s_part[0][h_][kk0] + s_part[1][h_][kk0]) : -3.0e38f;
      v1 = (k0 + kk1 < cnt) ? (s_part[0][h_][kk1] + s_part[1][h_][kk1]) : -3.0e38f;
      red[h_][grp] = fmaxf(v0, v1);
    }
    __syncthreads();
    if (t < 16) {
      float mc = red[t][0];
#pragma unroll
      for (int g = 1; g < 16; g++) mc = fmaxf(mc, red[t][g]);
      float mo = m_sh[t], mn = fmaxf(mo, mc);
      m_sh[t] = mn;
      al_sh[t] = __expf(mo - mn);
    }
    __syncthreads();
    {
      float mm = m_sh[h_];
      float e0 = __expf(v0 - mm), e1 = __expf(v1 - mm);
      p_bf[h_][grp * 2] = f2bf(e0);
      p_bf[h_][grp * 2 + 1] = f2bf(e1);
      red[h_][grp] = e0 + e1;
    }
    __syncthreads();
    if (t < 16) {
      float sl = 0.f;
#pragma unroll
      for (int g = 0; g < 16; g++) sl += red[t][g];
      l_sh[t] = l_sh[t] * al_sh[t] + sl;
    }
    __syncthreads();
    // PV via MFMA: A = P[h][key] (m=h), B = V[key][c] from c-pair dwords (even/odd split)
    {
      bf16x8 pa = *(const bf16x8*)&p_bf[ln][quad * 8];
      float al0 = al_sh[quad * 4 + 0], al1 = al_sh[quad * 4 + 1];
      float al2 = al_sh[quad * 4 + 2], al3 = al_sh[quad * 4 + 3];
#pragma unroll
      for (int i = 0; i < 8; i++) {
        o[i][0] *= al0; o[i][1] *= al1; o[i][2] *= al2; o[i][3] *= al3;
      }
#pragma unroll
      for (int tau = 0; tau < 4; tau++) {
        const unsigned* kp = &kvt2[(w * 64 + tau * 16 + ln) * 36 + quad * 8];
        uint4 lo = *(const uint4*)kp;
        uint4 hi = *(const uint4*)(kp + 4);
        unsigned ev[4], od[4];
        ev[0] = __builtin_amdgcn_perm(lo.y, lo.x, 0x05040100u);
        od[0] = __builtin_amdgcn_perm(lo.y, lo.x, 0x07060302u);
        ev[1] = __builtin_amdgcn_perm(lo.w, lo.z, 0x05040100u);
        od[1] = __builtin_amdgcn_perm(lo.w, lo.z, 0x07060302u);
        ev[2] = __builtin_amdgcn_perm(hi.y, hi.x, 0x05040100u);
        od[2] = __builtin_amdgcn_perm(hi.y, hi.x, 0x07060302u);
        ev[3] = __builtin_amdgcn_perm(hi.w, hi.z, 0x05040100u);
        od[3] = __builtin_amdgcn_perm(hi.w, hi.z, 0x07060302u);
        o[tau * 2]     = __builtin_amdgcn_mfma_f32_16x16x32_bf16(pa, *(const bf16x8*)ev, o[tau * 2], 0, 0, 0);
        o[tau * 2 + 1] = __builtin_amdgcn_mfma_f32_16x16x32_bf16(pa, *(const bf16x8*)od, o[tau * 2 + 1], 0, 0, 0);
      }
    }
  }
  __syncthreads();
  if (t < 16) l_sh[t] = 1.0f / l_sh[t];
  __syncthreads();
  {
    float li[4] = {l_sh[quad * 4 + 0], l_sh[quad * 4 + 1], l_sh[quad * 4 + 2], l_sh[quad * 4 + 3]};
#pragma unroll
    for (int tau = 0; tau < 4; tau++) {
      int c2 = w * 64 + tau * 16 + ln;
#pragma unroll
      for (int r = 0; r < 4; r++) {
        int h = quad * 4 + r;
        unsigned pk = (unsigned)f2bf(o[tau * 2][r] * li[r]) |
                      ((unsigned)f2bf(o[tau * 2 + 1][r] * li[r]) << 16);
        *(unsigned*)(o_c + (size_t)s * 8192 + h * 512 + 2 * c2) = pk;
      }
    }
  }
}

// ---------------- launch ----------------
extern "C" void kernel_launch(void* const* d_in, const int* in_sizes, int n_in,
                              void* d_out, int out_size, void* d_ws, size_t ws_size,
                              hipStream_t stream) {
  const float* hs         = (const float*)d_in[0];
  const float* cosp       = (const float*)d_in[1];
  const float* sinp       = (const float*)d_in[2];
  const float* w_q_a      = (const float*)d_in[3];
  const float* q_a_ln_w   = (const float*)d_in[4];
  const float* w_q_b      = (const float*)d_in[5];
  const float* w_kv_a     = (const float*)d_in[6];
  const float* kv_a_ln_w  = (const float*)d_in[7];
  const float* w_kv_b     = (const float*)d_in[8];
  const float* w_o        = (const float*)d_in[9];
  const float* idx_wq_b   = (const float*)d_in[10];
  const float* idx_wk     = (const float*)d_in[11];
  const float* idx_k_ln_w = (const float*)d_in[12];
  const float* idx_k_ln_b = (const float*)d_in[13];
  const float* idx_w_proj = (const float*)d_in[14];
  float* out = (float*)d_out;

  // ---- compact workspace layout (floats); total 45,320,192 f = 181.3 MB ----
  float* ws = (float*)d_ws;
  float*          qb      = ws;                                   // 6,291,456 f
  float*          cq      = ws + 6291456;                         // 3,145,728 f (dead after rmsnorm)
  unsigned short* qbbf    = (unsigned short*)cq;                  //   alias: 3,145,728 sh
  unsigned short* cqbf    = (unsigned short*)(ws + 9437184);      // 3,145,728 sh
  float*          kvp     = ws + 11010048;                        // 1,310,720 f
  unsigned short* kvbf    = (unsigned short*)(ws + 12320768);     // 1,179,648 sh
  float*          wts     = ws + 12910592;                        // 32,768 f
  int*            sel     = (int*)(ws + 12943360);                // 2,097,152 i
  int*            selcnt  = sel + 2097152;                        // 2,048 i
  float*          ki      = ws + 15042560;                        // 262,144 f
  unsigned short* kibf    = (unsigned short*)(ws + 15304704);     // 262,144 sh
  unsigned short* wkvbbf  = (unsigned short*)(ws + 15435776);     // 2,097,152 sh (512x4096)
  unsigned short* wvT     = (unsigned short*)(ws + 16484352);     // 1,048,576 sh
  unsigned short* attnbbf = (unsigned short*)(ws + 17008640);     // 4,194,304 sh
  unsigned short* o_c     = (unsigned short*)(ws + 19105792);     // 16,777,216 sh
  unsigned short* woT     = o_c;                                  //   alias (o_c dead after wv gemm)
  unsigned short* hsbf    = (unsigned short*)(ws + 27494400);     // 8,388,608 sh
  float*          qi      = ws + 31688704;                        // 4,194,304 f
  unsigned short* qibf    = (unsigned short*)(ws + 35883008);     // 4,194,304 sh
  float*          isc     = ws + 37980160;                        // 4,194,304 f
  unsigned short* qfull   = (unsigned short*)qi;                  //   alias: needs 18,874,368 sh = 9,437,184 f
                                                                  //   fits in qi+qibf+isc = 10,485,760 f (dead after topk)
  unsigned short* wT      = (unsigned short*)(ws + 42174464);     // 6,291,456 sh transpose scratch

  const float qscale = 0.07216878364870322f;  // 192^-0.5

  // 1. casts / cq path
  cast_bf16<<<4096, 256, 0, stream>>>(hs, hsbf);
  transpose_cast<<<dim3(48, 64), 256, 0, stream>>>(w_q_a, wT, 4096, 1536);
  gemm_bf16x<<<dim3(12, 16, 1), 256, 0, stream>>>(hsbf, wT, cq, 4096, 4096, 4096, 1536, 0, 0, 0);
  rmsnorm_bf16_kernel<<<2048, 256, 0, stream>>>(cq, q_a_ln_w, cqbf, 1536, 1536);

  // 2. indexer path (qi/qibf/isc live only until topk)
  transpose_cast<<<dim3(64, 24), 256, 0, stream>>>(idx_wq_b, wT, 1536, 2048);
  gemm_bf16x<<<dim3(16, 16, 1), 256, 0, stream>>>(cqbf, wT, qi, 1536, 1536, 1536, 2048, 0, 0, 0);
  rope_qi_nonint<<<4096, 256, 0, stream>>>(qi, cosp, sinp);
  cast_bf16<<<2048, 256, 0, stream>>>(qi, qibf);
  transpose_cast<<<dim3(4, 64), 256, 0, stream>>>(idx_wk, wT, 4096, 128);
  gemm_bf16x<<<dim3(1, 16, 1), 256, 0, stream>>>(hsbf, wT, ki, 4096, 4096, 4096, 128, 0, 0, 0);
  layernorm128_kernel<<<2048, 128, 0, stream>>>(ki, idx_k_ln_w, idx_k_ln_b);
  rope_ki_nonint<<<256, 256, 0, stream>>>(ki, cosp, sinp);
  cast_bf16<<<128, 256, 0, stream>>>(ki, kibf);
  wts_kernel<<<2048, 256, 0, stream>>>(hs, idx_w_proj, wts);
  indexer_mfma<<<528, 256, 0, stream>>>(qibf, kibf, wts, isc);
  topk_select<<<2048, 256, 0, stream>>>(isc, sel, selcnt);

  // 3. q path
  transpose_cast<<<dim3(96, 24), 256, 0, stream>>>(w_q_b, wT, 1536, 3072);
  gemm_bf16x<<<dim3(24, 16, 1), 256, 0, stream>>>(cqbf, wT, qb, 1536, 1536, 1536, 3072, 0, 0, 0);
  rope_q_inter<<<4096, 256, 0, stream>>>(qb, cosp, sinp);
  cast_bf16<<<3072, 256, 0, stream>>>(qb, qbbf);

  // 4. kv path (padded N=640)
  transpose_cast<<<dim3(20, 64), 256, 0, stream>>>(w_kv_a, wT, 4096, 576);
  gemm_bf16x<<<dim3(5, 16, 1), 256, 0, stream>>>(hsbf, wT, kvp, 4096, 4096, 4096, 640, 0, 0, 0);
  rmsnorm_kernel<<<2048, 256, 0, stream>>>(kvp, kv_a_ln_w, 512, 640);
  rope_k_inter<<<256, 256, 0, stream>>>(kvp, cosp, sinp, 640);
  kv_to_bf16_pad<<<2048, 256, 0, stream>>>(kvp, kvbf);

  // 5. absorbed q: qfull[s][h*576 + 0..511] = (q_nope @ w_k[h]^T)*qscale ; [512..575] = rope*qscale
  // w_kv_b is 512x4096 = 2,097,152 elems -> 1024 blocks (R4 bug: 8192 blocks read 56MB OOB)
  cast_bf16<<<1024, 256, 0, stream>>>(w_kv_b, wkvbbf);
  gemm_bf16x_bf<<<dim3(4, 16, 16), 256, 0, stream>>>(qbbf, wkvbbf, qfull,
                                                     128, 3072, 4096, 9216, 192, 256, 576, qscale);
  qfull_rope<<<4096, 256, 0, stream>>>(qb, qfull);

  // 6. flash attention
  flash_attn2<<<2048, 256, 0, stream>>>(qfull, kvbf, sel, o_c);

  // 7. attn_out[s][h*128+d] = o_c[s][h*512+:] @ w_v[h]
  transpose_wv<<<dim3(4, 16), 256, 0, stream>>>(wkvbbf, wvT);
  gemm_bf16x_bf<<<dim3(1, 16, 16), 256, 0, stream>>>(o_c, wvT, attnbbf,
                                                     512, 8192, 512, 2048, 512, 65536, 128, 1.0f);

  // 8. out = attn_out @ w_o (woT aliases o_c, dead)
  transpose_cast<<<dim3(128, 32), 256, 0, stream>>>(w_o, woT, 2048, 4096);
  gemm_bf16x<<<dim3(32, 16, 1), 256, 0, stream>>>(attnbbf, woT, out, 2048, 2048, 2048, 4096, 0, 0, 0);
}